// Round 14
// baseline (470.143 us; speedup 1.0000x reference)
//
#include <hip/hip_runtime.h>
#include <math.h>

// Problem constants (from reference setup_inputs)
#define NN    5000      // nodes
#define NE    80000     // edges
#define NB    32        // batch
#define DIN   16        // input feat
#define CH    64        // conv channels
#define KPOOL 30
#define FTOT  208      // 16 + 3*64
#define FLATW 6241     // KPOOL*FTOT + 1
#define NH    128      // MLP hidden
#define NPB   16       // nodes per block (4 per wave)
#define NEPAD (NE + 4 * NN)   // CSR rows padded to multiple of 4
#define NSLOT 64       // stats atomic-spread slots

// h tensors use BATCH-SPLIT NODE-MAJOR layout with G=16: (16, N, 2, 64).
// Per-group gather working set = N*2*64*4B = 2.56 MB < 4 MiB XCD L2 -> gather
// is L2-resident (R13's G=8 had 5.1 MB -> 114 MB HBM refetch).
// xt keeps G=8 layout (G8, N, 4, 16): 1.28 MB already fits.

// ---------------- setup kernels ----------------

__global__ void k_init(float* deg, int* counts, float* stats, float* hm) {
    int i = blockIdx.x * 256 + threadIdx.x;
    if (i < NN) { deg[i] = 1.0f; counts[i] = 0; }   // deg starts at self-loop value 1
    if (i < 2 * NSLOT * 128) stats[i] = 0.0f;       // [2 layers][64 slots][128]
    if (i < 4096) hm[i] = 0.0f;
}

// merged: edge-degree atomics (blocks 0..312) + x transpose (blocks 313..937)
#define NEB 313
__global__ void k_edgetr(const float* __restrict__ attr, const int* __restrict__ erow,
                         float* deg, int* counts,
                         const float* __restrict__ x, float* __restrict__ xt) {
    if (blockIdx.x < NEB) {
        int e = blockIdx.x * 256 + threadIdx.x;
        if (e < NE) {
            int r = erow[e];
            atomicAdd(&deg[r], attr[e]);
            atomicAdd(&counts[r], 1);
        }
    } else {
        int idx = (blockIdx.x - NEB) * 256 + threadIdx.x;
        if (idx >= NB * NN) return;
        int b = idx / NN, n = idx % NN;
        int g = b >> 2, bi = b & 3;
        const float4* src = (const float4*)(x + (size_t)idx * DIN);
        float4* dst = (float4*)(xt + (((size_t)g * NN + n) * 4 + bi) * DIN);
        dst[0] = src[0]; dst[1] = src[1]; dst[2] = src[2]; dst[3] = src[3];
    }
}

// scan PADDED counts (rounded up to mult of 4) + dinv; wave-shuffle scan
__global__ __launch_bounds__(1024) void k_scan(const int* __restrict__ counts,
                                               const float* __restrict__ deg,
                                               int* rowptr, int* cursor, float* dinv) {
    __shared__ int wsum[16], woff[16];
    __shared__ int carry_sh;
    int t = threadIdx.x;
    int lane = t & 63, wid = t >> 6;
    if (t == 0) carry_sh = 0;
    __syncthreads();
    for (int base = 0; base < NN; base += 1024) {
        int carry = carry_sh;
        int i = base + t;
        int v = 0;
        if (i < NN) {
            v = (counts[i] + 3) & ~3;
            dinv[i] = 1.0f / sqrtf(deg[i]);   // deg >= 1 always
        }
        int s = v;
#pragma unroll
        for (int off = 1; off < 64; off <<= 1) {
            int o = __shfl_up(s, off);
            if (lane >= off) s += o;
        }
        if (lane == 63) wsum[wid] = s;
        __syncthreads();
        if (t < 16) {
            int w = wsum[t];
#pragma unroll
            for (int off = 1; off < 16; off <<= 1) {
                int o = __shfl_up(w, off);
                if (t >= off) w += o;
            }
            woff[t] = w;
        }
        __syncthreads();
        int inc = s + (wid > 0 ? woff[wid - 1] : 0) + carry;
        if (i < NN) {
            rowptr[i + 1] = inc;
            cursor[i] = inc - v;
        }
        if (t == 1023) carry_sh = carry + woff[15];
        __syncthreads();
    }
    if (t == 0) rowptr[0] = 0;
}

// merged: CSR scatter (t < NE) + zero-weight pad fill (t-NE < NN); disjoint slots
__global__ void k_build(const int* __restrict__ erow, const int* __restrict__ ecol,
                        const float* __restrict__ attr, const float* __restrict__ dinv,
                        const int* __restrict__ counts, const int* __restrict__ rowptr,
                        int* cursor, int* csr_col, float* csr_nv) {
    int t = blockIdx.x * 256 + threadIdx.x;
    if (t < NE) {
        int r = erow[t], c = ecol[t];
        int pos = atomicAdd(&cursor[r], 1);
        csr_col[pos] = c;
        csr_nv[pos] = dinv[r] * attr[t] * dinv[c];
    } else if (t - NE < NN) {
        int i = t - NE;
        int cnt = counts[i];
        int pcnt = (cnt + 3) & ~3;
        int base = rowptr[i + 1] - pcnt;
        for (int p = base + cnt; p < base + pcnt; ++p) { csr_col[p] = i; csr_nv[p] = 0.0f; }
    }
}

// ---------------- helpers ----------------
template<int ACT>
__device__ __forceinline__ float4 actv(float4 v, float4 s, float4 t) {
    if (ACT) {
        v.x = fmaxf(fmaf(v.x, s.x, t.x), 0.f);
        v.y = fmaxf(fmaf(v.y, s.y, t.y), 0.f);
        v.z = fmaxf(fmaf(v.z, s.z, t.z), 0.f);
        v.w = fmaxf(fmaf(v.w, s.w, t.w), 0.f);
    }
    return v;
}
template<int ACT>
__device__ __forceinline__ float2 actv2(float2 v, float2 s, float2 t) {
    if (ACT) {
        v.x = fmaxf(fmaf(v.x, s.x, t.x), 0.f);
        v.y = fmaxf(fmaf(v.y, s.y, t.y), 0.f);
    }
    return v;
}
__device__ __forceinline__ void fma4(float4& a, float w, float4 v) {
    a.x = fmaf(w, v.x, a.x); a.y = fmaf(w, v.y, a.y);
    a.z = fmaf(w, v.z, a.z); a.w = fmaf(w, v.w, a.w);
}

// ---------------- fused GCN layer ----------------
// CIN=64: block = (16 nodes, group g of 2 batches), grid = 313*16. Wave owns
// 4 nodes; gather = float2/lane (512 B/wave row, L2-resident slice).
// CIN=16: block = (16 nodes, g of 4 batches), grid = 313*8 (xt is G8 layout).
// Stage 2: R9 codegen shape (W float4 global + scalar LDS A; don't vectorize
// A reads — R10 regression). Output always written in G16 (16,N,2,64) layout.
// STATS: slot-spread atomic BN sum/sumsq epilogue (64 slots).
template<int CIN, int ACT, int STATS>
__global__ __launch_bounds__(256) void k_layer(
        const float* __restrict__ in, const float* __restrict__ bnstats,
        const float* __restrict__ gamma, const float* __restrict__ beta,
        const float* __restrict__ W, const float* __restrict__ bias,
        const int* __restrict__ rowptr, const int* __restrict__ csr_col,
        const float* __restrict__ csr_nv, const float* __restrict__ dinv,
        float* __restrict__ out, float* __restrict__ stats) {
    constexpr int ALS  = (CIN == 64) ? 68 : 20;
    constexpr int ROWS = (CIN == 64) ? 8 : 16;
    constexpr int GSH  = (CIN == 64) ? 4 : 3;
    constexpr int GMSK = (1 << GSH) - 1;
    __shared__ float As[4 * ROWS * ALS];
    __shared__ float stl[ACT ? 128 : 4];
    int tid = threadIdx.x;
    int wid = tid >> 6, lane = tid & 63;
    int g = blockIdx.x & GMSK;                   // XCD round-robin
    int nb = (blockIdx.x >> GSH) * NPB;
    int base = nb + wid * 4;
    float* Aw = As + wid * ROWS * ALS;

    if (ACT) {
        if (tid < 64) {
            float su = 0.f, qu = 0.f;
            for (int s = 0; s < NSLOT; ++s) {
                su += bnstats[s * 128 + tid];
                qu += bnstats[s * 128 + 64 + tid];
            }
            const float inv = 1.0f / (float)(NB * NN);
            float mu = su * inv;
            float var = qu * inv - mu * mu;
            float sc = gamma[tid] / sqrtf(var + 1e-5f);
            stl[tid] = sc;
            stl[64 + tid] = fmaf(-mu, sc, beta[tid]);
        }
        __syncthreads();
    }

    if (CIN == 64) {
        // ---- stage 1: gather, float2/lane; in = (G16,N,2,64) ----
        const float2* __restrict__ in2 = (const float2*)in + (size_t)g * NN * 64;
        int c2 = lane & 31;        // channel pair
        int bi = lane >> 5;        // batch within group (unused directly; row addr via lane)
        (void)bi;
        float2 sv = {1.f,1.f}, tv = {0.f,0.f};
        if (ACT) { sv = ((const float2*)stl)[c2]; tv = ((const float2*)(stl + 64))[c2]; }
#pragma unroll
        for (int i = 0; i < 4; ++i) {
            int r = base + i;
            float2 a = {0.f, 0.f};
            if (r < NN) {
                float d = dinv[r];
                float dd = d * d;
                float2 v = actv2<ACT>(in2[(size_t)r * 64 + lane], sv, tv);
                a.x = dd * v.x; a.y = dd * v.y;
                int p0 = rowptr[r], p1 = rowptr[r + 1];   // multiples of 4
                for (int e = p0; e < p1; e += 4) {
                    int4   cc = *(const int4*)(csr_col + e);
                    float4 ww = *(const float4*)(csr_nv + e);
                    float2 v0 = in2[(size_t)cc.x * 64 + lane];
                    float2 v1 = in2[(size_t)cc.y * 64 + lane];
                    float2 v2 = in2[(size_t)cc.z * 64 + lane];
                    float2 v3 = in2[(size_t)cc.w * 64 + lane];
                    v0 = actv2<ACT>(v0, sv, tv);
                    a.x = fmaf(ww.x, v0.x, a.x); a.y = fmaf(ww.x, v0.y, a.y);
                    v1 = actv2<ACT>(v1, sv, tv);
                    a.x = fmaf(ww.y, v1.x, a.x); a.y = fmaf(ww.y, v1.y, a.y);
                    v2 = actv2<ACT>(v2, sv, tv);
                    a.x = fmaf(ww.z, v2.x, a.x); a.y = fmaf(ww.z, v2.y, a.y);
                    v3 = actv2<ACT>(v3, sv, tv);
                    a.x = fmaf(ww.w, v3.x, a.x); a.y = fmaf(ww.w, v3.y, a.y);
                }
            }
            // row = node_i*2 + bi, channel pair c2
            *(float2*)(Aw + (i * 2 + (lane >> 5)) * ALS + c2 * 2) = a;
        }
    } else {
        // ---- stage 1 (CIN=16): in = xt (G8,N,4,16), row = 64 floats ----
        const float* __restrict__ inr = in + (size_t)g * NN * 64;
#pragma unroll
        for (int i = 0; i < 4; ++i) {
            int r = base + i;
            float a = 0.f;
            if (r < NN) {
                float d = dinv[r];
                a = d * d * inr[(size_t)r * 64 + lane];
                int p0 = rowptr[r], p1 = rowptr[r + 1];
                for (int e = p0; e < p1; e += 4) {
                    int4   cc = *(const int4*)(csr_col + e);
                    float4 ww = *(const float4*)(csr_nv + e);
                    float v0 = inr[(size_t)cc.x * 64 + lane];
                    float v1 = inr[(size_t)cc.y * 64 + lane];
                    float v2 = inr[(size_t)cc.z * 64 + lane];
                    float v3 = inr[(size_t)cc.w * 64 + lane];
                    a = fmaf(ww.x, v0, a);
                    a = fmaf(ww.y, v1, a);
                    a = fmaf(ww.z, v2, a);
                    a = fmaf(ww.w, v3, a);
                }
            }
            Aw[(i * 4 + (lane >> 4)) * ALS + (lane & 15)] = a;
        }
    }
    __syncthreads();

    // ---- stage 2: per-wave GEMM [R9 scalar-A shape] ----
    int colq = lane & 15;
    const float4* __restrict__ W4 = (const float4*)W;
    float4 bb = ((const float4*)bias)[colq];

    if (CIN == 64) {
        int rowhalf = lane >> 4;            // rows rowhalf and rowhalf+4 of 8
        float4 o0 = bb, o1 = bb;
#pragma unroll 8
        for (int k = 0; k < 64; ++k) {
            float4 w4 = W4[k * 16 + colq];
            float a0 = Aw[rowhalf * ALS + k];
            float a1 = Aw[(rowhalf + 4) * ALS + k];
            fma4(o0, a0, w4);
            fma4(o1, a1, w4);
        }
        int bi2 = rowhalf & 1;
        int n0 = base + (rowhalf >> 1);
        int n1 = n0 + 2;
        if (n0 < NN)
            ((float4*)(out + (((size_t)g * NN + n0) * 2 + bi2) * 64))[colq] = o0;
        if (n1 < NN)
            ((float4*)(out + (((size_t)g * NN + n1) * 2 + bi2) * 64))[colq] = o1;

        if (STATS) {
            float4 s4 = {0,0,0,0}, q4 = {0,0,0,0};
            if (n0 < NN) {
                s4.x += o0.x; s4.y += o0.y; s4.z += o0.z; s4.w += o0.w;
                q4.x = fmaf(o0.x, o0.x, q4.x); q4.y = fmaf(o0.y, o0.y, q4.y);
                q4.z = fmaf(o0.z, o0.z, q4.z); q4.w = fmaf(o0.w, o0.w, q4.w);
            }
            if (n1 < NN) {
                s4.x += o1.x; s4.y += o1.y; s4.z += o1.z; s4.w += o1.w;
                q4.x = fmaf(o1.x, o1.x, q4.x); q4.y = fmaf(o1.y, o1.y, q4.y);
                q4.z = fmaf(o1.z, o1.z, q4.z); q4.w = fmaf(o1.w, o1.w, q4.w);
            }
            s4.x += __shfl_xor(s4.x, 16); s4.y += __shfl_xor(s4.y, 16);
            s4.z += __shfl_xor(s4.z, 16); s4.w += __shfl_xor(s4.w, 16);
            q4.x += __shfl_xor(q4.x, 16); q4.y += __shfl_xor(q4.y, 16);
            q4.z += __shfl_xor(q4.z, 16); q4.w += __shfl_xor(q4.w, 16);
            s4.x += __shfl_xor(s4.x, 32); s4.y += __shfl_xor(s4.y, 32);
            s4.z += __shfl_xor(s4.z, 32); s4.w += __shfl_xor(s4.w, 32);
            q4.x += __shfl_xor(q4.x, 32); q4.y += __shfl_xor(q4.y, 32);
            q4.z += __shfl_xor(q4.z, 32); q4.w += __shfl_xor(q4.w, 32);
            __syncthreads();
            if (lane < 16) {
                float* S = As + wid * 128;
                *(float4*)(S + lane * 8) = s4;
                *(float4*)(S + lane * 8 + 4) = q4;
            }
            __syncthreads();
            if (tid < 64) {
                int cq = tid >> 2, comp = tid & 3;
                float s = 0.f, q = 0.f;
#pragma unroll
                for (int w = 0; w < 4; ++w) {
                    s += As[w * 128 + cq * 8 + comp];
                    q += As[w * 128 + cq * 8 + 4 + comp];
                }
                float* sl = stats + (blockIdx.x & (NSLOT - 1)) * 128;
                atomicAdd(&sl[tid], s);
                atomicAdd(&sl[64 + tid], q);
            }
        }
    } else {
        int rowq = lane >> 4;
        int node = base + rowq;
        float4 o[4];
#pragma unroll
        for (int i = 0; i < 4; ++i) o[i] = bb;
#pragma unroll 8
        for (int k = 0; k < CIN; ++k) {
            float4 w4 = W4[k * 16 + colq];
#pragma unroll
            for (int i = 0; i < 4; ++i) {
                float a = Aw[(rowq * 4 + i) * ALS + k];
                fma4(o[i], a, w4);
            }
        }
        if (node < NN) {
#pragma unroll
            for (int i = 0; i < 4; ++i) {   // bi=i of 4 batches -> G16 rows
                size_t row = ((size_t)(2 * g + (i >> 1)) * NN + node) * 2 + (i & 1);
                ((float4*)(out + row * 64))[colq] = o[i];
            }
        }

        if (STATS) {
            float4 s4 = {0,0,0,0}, q4 = {0,0,0,0};
            if (node < NN) {
#pragma unroll
                for (int i = 0; i < 4; ++i) {
                    s4.x += o[i].x; s4.y += o[i].y; s4.z += o[i].z; s4.w += o[i].w;
                    q4.x = fmaf(o[i].x, o[i].x, q4.x); q4.y = fmaf(o[i].y, o[i].y, q4.y);
                    q4.z = fmaf(o[i].z, o[i].z, q4.z); q4.w = fmaf(o[i].w, o[i].w, q4.w);
                }
            }
            s4.x += __shfl_xor(s4.x, 16); s4.y += __shfl_xor(s4.y, 16);
            s4.z += __shfl_xor(s4.z, 16); s4.w += __shfl_xor(s4.w, 16);
            q4.x += __shfl_xor(q4.x, 16); q4.y += __shfl_xor(q4.y, 16);
            q4.z += __shfl_xor(q4.z, 16); q4.w += __shfl_xor(q4.w, 16);
            s4.x += __shfl_xor(s4.x, 32); s4.y += __shfl_xor(s4.y, 32);
            s4.z += __shfl_xor(s4.z, 32); s4.w += __shfl_xor(s4.w, 32);
            q4.x += __shfl_xor(q4.x, 32); q4.y += __shfl_xor(q4.y, 32);
            q4.z += __shfl_xor(q4.z, 32); q4.w += __shfl_xor(q4.w, 32);
            __syncthreads();
            if (lane < 16) {
                float* S = As + wid * 128;
                *(float4*)(S + lane * 8) = s4;
                *(float4*)(S + lane * 8 + 4) = q4;
            }
            __syncthreads();
            if (tid < 64) {
                int cq = tid >> 2, comp = tid & 3;
                float s = 0.f, q = 0.f;
#pragma unroll
                for (int w = 0; w < 4; ++w) {
                    s += As[w * 128 + cq * 8 + comp];
                    q += As[w * 128 + cq * 8 + 4 + comp];
                }
                float* sl = stats + (blockIdx.x & (NSLOT - 1)) * 128;
                atomicAdd(&sl[tid], s);
                atomicAdd(&sl[64 + tid], q);
            }
        }
    }
}

// ---------------- global_sort_pool: register top-30, packed-u64 stable keys ----
__global__ __launch_bounds__(1024) void k_toppool(const float* __restrict__ h3, int* order) {
    __shared__ unsigned long long wbest[16];
    __shared__ unsigned long long winner;
    int b = blockIdx.x, tid = threadIdx.x;
    int g = b >> 1, bi = b & 1;          // G16 layout
    int lane = tid & 63, wid = tid >> 6;
    unsigned long long key[5];
#pragma unroll
    for (int j = 0; j < 5; ++j) {
        int n = tid + j * 1024;
        unsigned long long k = 0;
        if (n < NN) {
            float v = fmaxf(h3[(((size_t)g * NN + n) * 2 + bi) * 64 + 63], 0.f);
            k = ((unsigned long long)__float_as_uint(v) << 32) | (unsigned int)(NN - n);
        }
        key[j] = k;
    }
    for (int k = 0; k < KPOOL; ++k) {
        unsigned long long best = key[0];
#pragma unroll
        for (int j = 1; j < 5; ++j) best = (key[j] > best) ? key[j] : best;
#pragma unroll
        for (int off = 1; off < 64; off <<= 1) {
            unsigned long long o = __shfl_xor(best, off);
            best = (o > best) ? o : best;
        }
        if (lane == 0) wbest[wid] = best;
        __syncthreads();
        if (tid == 0) {
            unsigned long long w = wbest[0];
#pragma unroll
            for (int i = 1; i < 16; ++i) w = (wbest[i] > w) ? wbest[i] : w;
            winner = w;
            order[b * KPOOL + k] = NN - (int)(w & 0xFFFFFFFFu);
        }
        __syncthreads();
        int n = NN - (int)(winner & 0xFFFFFFFFu);
        if ((n & 1023) == tid) key[n >> 10] = 0;   // remove winner (owner thread)
    }
}

// ---------------- gather selected nodes into flat (B, 6241); inline BN coeffs ----
__global__ void k_gather(const float* __restrict__ xt, const float* __restrict__ h1,
                         const float* __restrict__ h2, const float* __restrict__ h3,
                         const float* __restrict__ stats,
                         const float* __restrict__ g0, const float* __restrict__ be0,
                         const float* __restrict__ g1, const float* __restrict__ be1,
                         const float* __restrict__ age,
                         const int* __restrict__ order, float* __restrict__ flat) {
    __shared__ float stl[256];
    int tid = threadIdx.x;
    if (tid < 128) {
        int layer = tid >> 6, c = tid & 63;
        const float* sb = stats + layer * NSLOT * 128;
        float su = 0.f, qu = 0.f;
        for (int s = 0; s < NSLOT; ++s) { su += sb[s * 128 + c]; qu += sb[s * 128 + 64 + c]; }
        const float inv = 1.0f / (float)(NB * NN);
        float mu = su * inv;
        float var = qu * inv - mu * mu;
        float gm = layer ? g1[c] : g0[c];
        float be = layer ? be1[c] : be0[c];
        float sc = gm / sqrtf(var + 1e-5f);
        stl[layer * 128 + c] = sc;
        stl[layer * 128 + 64 + c] = fmaf(-mu, sc, be);
    }
    __syncthreads();

    int bk = blockIdx.x;
    int b = bk / KPOOL, k = bk % KPOOL;
    int n = order[bk];
    size_t node2 = ((size_t)(b >> 1) * NN + n) * 2 + (b & 1);   // G16 index for h*
    int f = tid;
    float val = 0.f;
    if (f < DIN) {
        val = xt[(((size_t)(b >> 2) * NN + n) * 4 + (b & 3)) * DIN + f];
    } else if (f < DIN + CH) {
        int c = f - DIN;
        val = fmaxf(fmaf(h1[node2 * 64 + c], stl[c], stl[64 + c]), 0.f);
    } else if (f < DIN + 2 * CH) {
        int c = f - DIN - CH;
        val = fmaxf(fmaf(h2[node2 * 64 + c], stl[128 + c], stl[192 + c]), 0.f);
    } else if (f < FTOT) {
        int c = f - DIN - 2 * CH;
        val = fmaxf(h3[node2 * 64 + c], 0.f);
    }
    if (f < FTOT) flat[(size_t)b * FLATW + k * FTOT + f] = val;
    if (bk == 0 && f >= FTOT && f < FTOT + NB)
        flat[(size_t)(f - FTOT) * FLATW + (FLATW - 1)] = age[f - FTOT];
}

// ---------------- MLP head layer 1: hm += flat @ mW0 (k-split, atomics) ----------------
__global__ void k_head1(const float* __restrict__ flat, const float* __restrict__ mW0,
                        float* hm) {
    int tid = threadIdx.x;
    int j4 = (tid & 31) * 4;       // 32 groups * 4 = 128 cols
    int b0 = (tid >> 5) * 4;       // 8 groups * 4 = 32 rows
    int kbase = blockIdx.x * 64;
    float acc[4][4];
#pragma unroll
    for (int i = 0; i < 4; i++)
#pragma unroll
        for (int jj = 0; jj < 4; jj++) acc[i][jj] = 0.f;
    int kend = FLATW - kbase; if (kend > 64) kend = 64;
    for (int kk = 0; kk < kend; ++kk) {
        int k = kbase + kk;
        float4 w = *(const float4*)(mW0 + (size_t)k * NH + j4);
#pragma unroll
        for (int i = 0; i < 4; i++) {
            float fv = flat[(size_t)(b0 + i) * FLATW + k];
            acc[i][0] = fmaf(fv, w.x, acc[i][0]);
            acc[i][1] = fmaf(fv, w.y, acc[i][1]);
            acc[i][2] = fmaf(fv, w.z, acc[i][2]);
            acc[i][3] = fmaf(fv, w.w, acc[i][3]);
        }
    }
#pragma unroll
    for (int i = 0; i < 4; i++)
#pragma unroll
        for (int jj = 0; jj < 4; jj++)
            atomicAdd(&hm[(size_t)(b0 + i) * NH + j4 + jj], acc[i][jj]);
}

// ---------------- head layer 2 + log_softmax ----------------
__global__ void k_head2(const float* __restrict__ hm, const float* __restrict__ mb0,
                        const float* __restrict__ mW1, const float* __restrict__ mb1,
                        float* __restrict__ out) {
    __shared__ float vals[64];
    int tid = threadIdx.x;  // 64 = 32 b * 2 o
    int b = tid >> 1, o = tid & 1;
    float acc = mb1[o];
    for (int j = 0; j < NH; ++j) {
        float hv = fmaxf(hm[b * NH + j] + mb0[j], 0.f);
        acc = fmaf(hv, mW1[j * 2 + o], acc);
    }
    vals[tid] = acc;
    __syncthreads();
    float v0 = vals[b * 2], v1 = vals[b * 2 + 1];
    float m = fmaxf(v0, v1);
    float lse = m + logf(expf(v0 - m) + expf(v1 - m));
    out[tid] = acc - lse;
}

extern "C" void kernel_launch(void* const* d_in, const int* in_sizes, int n_in,
                              void* d_out, int out_size, void* d_ws, size_t ws_size,
                              hipStream_t stream) {
    const float* x    = (const float*)d_in[0];
    const float* age  = (const float*)d_in[1];
    const float* attr = (const float*)d_in[2];
    const float* W0   = (const float*)d_in[3];
    const float* b0   = (const float*)d_in[4];
    const float* W1   = (const float*)d_in[5];
    const float* b1   = (const float*)d_in[6];
    const float* W2   = (const float*)d_in[7];
    const float* b2   = (const float*)d_in[8];
    const float* g0   = (const float*)d_in[9];
    const float* be0  = (const float*)d_in[10];
    const float* g1   = (const float*)d_in[11];
    const float* be1  = (const float*)d_in[12];
    const float* mW0  = (const float*)d_in[13];
    const float* mb0  = (const float*)d_in[14];
    const float* mW1  = (const float*)d_in[15];
    const float* mb1  = (const float*)d_in[16];
    const int* erow   = (const int*)d_in[17];
    const int* ecol   = (const int*)d_in[18];
    float* out = (float*)d_out;

    // workspace layout (floats); all float4-aligned
    float* ws     = (float*)d_ws;
    float* deg    = ws;                                  // 5008
    float* dinv   = deg + 5008;                          // 5008
    int*   counts = (int*)(dinv + 5008);                 // 5008
    int*   rowptr = counts + 5008;                       // 5008
    int*   cursor = rowptr + 5008;                       // 5008
    int*   csr_col= cursor + 5008;                       // NEPAD
    float* csr_nv = (float*)(csr_col + NEPAD);           // NEPAD
    float* stats  = csr_nv + NEPAD;                      // 2*64*128 = 16384
    int*   order  = (int*)(stats + 2 * NSLOT * 128);     // 960
    float* flat   = (float*)(order + 960);               // 32*6241
    float* hm     = flat + (size_t)NB * FLATW;           // 4096
    float* xt     = hm + 4096;                           // (G8,N,4,16)
    float* h1     = xt + (size_t)NB * NN * DIN;          // (G16,N,2,64) each
    float* h2     = h1 + (size_t)NB * NN * CH;
    float* h3     = h2 + (size_t)NB * NN * CH;

    // graph build
    k_init<<<64, 256, 0, stream>>>(deg, counts, stats, hm);
    k_edgetr<<<NEB + (NB * NN + 255) / 256, 256, 0, stream>>>(attr, erow, deg, counts, x, xt);
    k_scan<<<1, 1024, 0, stream>>>(counts, deg, rowptr, cursor, dinv);
    k_build<<<(NE + NN + 255) / 256, 256, 0, stream>>>(erow, ecol, attr, dinv, counts, rowptr, cursor, csr_col, csr_nv);

    const int NBLK0 = ((NN + NPB - 1) / NPB) * 8;    // 313 * 8  (layer 0, G8 input)
    const int NBLK1 = ((NN + NPB - 1) / NPB) * 16;   // 313 * 16 (layers 1-2, G16)
    k_layer<16, 0, 1><<<NBLK0, 256, 0, stream>>>(xt, nullptr, nullptr, nullptr, W0, b0, rowptr, csr_col, csr_nv, dinv, h1, stats);
    k_layer<64, 1, 1><<<NBLK1, 256, 0, stream>>>(h1, stats, g0, be0, W1, b1, rowptr, csr_col, csr_nv, dinv, h2, stats + NSLOT * 128);
    k_layer<64, 1, 0><<<NBLK1, 256, 0, stream>>>(h2, stats + NSLOT * 128, g1, be1, W2, b2, rowptr, csr_col, csr_nv, dinv, h3, nullptr);

    // sort-pool + gather (inline BN coeffs) + head
    k_toppool<<<NB, 1024, 0, stream>>>(h3, order);
    k_gather<<<NB * KPOOL, 256, 0, stream>>>(xt, h1, h2, h3, stats, g0, be0, g1, be1, age, order, flat);
    k_head1<<<(FLATW + 63) / 64, 256, 0, stream>>>(flat, mW0, hm);
    k_head2<<<1, 64, 0, stream>>>(hm, mb0, mW1, mb1, out);
}

// Round 15
// 369.302 us; speedup vs baseline: 1.2731x; 1.2731x over previous
//
#include <hip/hip_runtime.h>
#include <math.h>

// Problem constants (from reference setup_inputs)
#define NN    5000      // nodes
#define NE    80000     // edges
#define NB    32        // batch
#define DIN   16        // input feat
#define CH    64        // conv channels
#define KPOOL 30
#define FTOT  208      // 16 + 3*64
#define FLATW 6241     // KPOOL*FTOT + 1
#define NH    128      // MLP hidden
#define NG    8        // batch groups (one per XCD; G>8 useless: 2 groups share an XCD — R14)
#define GB    4        // batches per group
#define NPB   16       // nodes per block (4 per wave)
#define NEPAD (NE + 4 * NN)   // CSR rows padded to multiple of 4
#define NSLOT 32       // stats atomic-spread slots (contention 2504 -> ~78)

// Feature tensors use BATCH-SPLIT NODE-MAJOR layout: (G=8, N, 4, C).

// ---------------- setup kernels ----------------

__global__ void k_init(float* deg, int* counts, float* stats, float* hm) {
    int i = blockIdx.x * 256 + threadIdx.x;
    if (i < NN) { deg[i] = 1.0f; counts[i] = 0; }   // deg starts at self-loop value 1
    if (i < 2 * NSLOT * 128) stats[i] = 0.0f;       // [2 layers][32 slots][128]
    if (i < 4096) hm[i] = 0.0f;
}

// merged: edge-degree atomics (blocks 0..312) + x transpose (blocks 313..937)
#define NEB 313
__global__ void k_edgetr(const float* __restrict__ attr, const int* __restrict__ erow,
                         float* deg, int* counts,
                         const float* __restrict__ x, float* __restrict__ xt) {
    if (blockIdx.x < NEB) {
        int e = blockIdx.x * 256 + threadIdx.x;
        if (e < NE) {
            int r = erow[e];
            atomicAdd(&deg[r], attr[e]);
            atomicAdd(&counts[r], 1);
        }
    } else {
        int idx = (blockIdx.x - NEB) * 256 + threadIdx.x;
        if (idx >= NB * NN) return;
        int b = idx / NN, n = idx % NN;
        int g = b >> 2, bi = b & 3;
        const float4* src = (const float4*)(x + (size_t)idx * DIN);
        float4* dst = (float4*)(xt + (((size_t)g * NN + n) * GB + bi) * DIN);
        dst[0] = src[0]; dst[1] = src[1]; dst[2] = src[2]; dst[3] = src[3];
    }
}

// scan PADDED counts (rounded up to mult of 4) + dinv; wave-shuffle scan
__global__ __launch_bounds__(1024) void k_scan(const int* __restrict__ counts,
                                               const float* __restrict__ deg,
                                               int* rowptr, int* cursor, float* dinv) {
    __shared__ int wsum[16], woff[16];
    __shared__ int carry_sh;
    int t = threadIdx.x;
    int lane = t & 63, wid = t >> 6;
    if (t == 0) carry_sh = 0;
    __syncthreads();
    for (int base = 0; base < NN; base += 1024) {
        int carry = carry_sh;
        int i = base + t;
        int v = 0;
        if (i < NN) {
            v = (counts[i] + 3) & ~3;
            dinv[i] = 1.0f / sqrtf(deg[i]);   // deg >= 1 always
        }
        int s = v;
#pragma unroll
        for (int off = 1; off < 64; off <<= 1) {
            int o = __shfl_up(s, off);
            if (lane >= off) s += o;
        }
        if (lane == 63) wsum[wid] = s;
        __syncthreads();
        if (t < 16) {
            int w = wsum[t];
#pragma unroll
            for (int off = 1; off < 16; off <<= 1) {
                int o = __shfl_up(w, off);
                if (t >= off) w += o;
            }
            woff[t] = w;
        }
        __syncthreads();
        int inc = s + (wid > 0 ? woff[wid - 1] : 0) + carry;
        if (i < NN) {
            rowptr[i + 1] = inc;
            cursor[i] = inc - v;
        }
        if (t == 1023) carry_sh = carry + woff[15];
        __syncthreads();
    }
    if (t == 0) rowptr[0] = 0;
}

// merged: CSR scatter (t < NE) + zero-weight pad fill (t-NE < NN); disjoint slots
__global__ void k_build(const int* __restrict__ erow, const int* __restrict__ ecol,
                        const float* __restrict__ attr, const float* __restrict__ dinv,
                        const int* __restrict__ counts, const int* __restrict__ rowptr,
                        int* cursor, int* csr_col, float* csr_nv) {
    int t = blockIdx.x * 256 + threadIdx.x;
    if (t < NE) {
        int r = erow[t], c = ecol[t];
        int pos = atomicAdd(&cursor[r], 1);
        csr_col[pos] = c;
        csr_nv[pos] = dinv[r] * attr[t] * dinv[c];
    } else if (t - NE < NN) {
        int i = t - NE;
        int cnt = counts[i];
        int pcnt = (cnt + 3) & ~3;
        int base = rowptr[i + 1] - pcnt;
        for (int p = base + cnt; p < base + pcnt; ++p) { csr_col[p] = i; csr_nv[p] = 0.0f; }
    }
}

// ---------------- helpers ----------------
template<int ACT>
__device__ __forceinline__ float4 actv(float4 v, float4 s, float4 t) {
    if (ACT) {
        v.x = fmaxf(fmaf(v.x, s.x, t.x), 0.f);
        v.y = fmaxf(fmaf(v.y, s.y, t.y), 0.f);
        v.z = fmaxf(fmaf(v.z, s.z, t.z), 0.f);
        v.w = fmaxf(fmaf(v.w, s.w, t.w), 0.f);
    }
    return v;
}
__device__ __forceinline__ void fma4(float4& a, float w, float4 v) {
    a.x = fmaf(w, v.x, a.x); a.y = fmaf(w, v.y, a.y);
    a.z = fmaf(w, v.z, a.z); a.w = fmaf(w, v.w, a.w);
}

// ---------------- fused GCN layer ----------------
// Block = (16 nodes, group g). Stage 0 (ACT): BN scale/shift from slot stats
// into LDS. Stage 1: 1 float4/lane acc per node; edge loop unrolled x4
// (padded CSR). Stage 2 (SCORE=0): R9 per-wave GEMM (W float4 global + scalar
// LDS A — do NOT vectorize A reads, R10 regression). Stage 2 (SCORE=1, last
// layer): h3 is only consumed at ch63 (sort) + 30 sel nodes — write agg from
// LDS + compact relu'd score column; full GEMM deferred to k_gather.
// STATS: slot-spread atomic BN sum/sumsq epilogue.
template<int CIN, int ACT, int STATS, int SCORE>
__global__ __launch_bounds__(256) void k_layer(
        const float* __restrict__ in, const float* __restrict__ bnstats,
        const float* __restrict__ gamma, const float* __restrict__ beta,
        const float* __restrict__ W, const float* __restrict__ bias,
        const int* __restrict__ rowptr, const int* __restrict__ csr_col,
        const float* __restrict__ csr_nv, const float* __restrict__ dinv,
        float* __restrict__ out, float* __restrict__ stats,
        float* __restrict__ score) {
    constexpr int ALS = (CIN == 64) ? 68 : 20;
    __shared__ float As[4 * 16 * ALS];
    __shared__ float stl[ACT ? 128 : 4];
    int tid = threadIdx.x;
    int wid = tid >> 6, lane = tid & 63;
    int g = blockIdx.x & 7;                      // XCD round-robin
    int nb = (blockIdx.x >> 3) * NPB;
    int base = nb + wid * 4;
    float* Aw = As + wid * 16 * ALS;

    if (ACT) {
        if (tid < 64) {
            float su = 0.f, qu = 0.f;
#pragma unroll
            for (int s = 0; s < NSLOT; ++s) {
                su += bnstats[s * 128 + tid];
                qu += bnstats[s * 128 + 64 + tid];
            }
            const float inv = 1.0f / (float)(NB * NN);
            float mu = su * inv;
            float var = qu * inv - mu * mu;
            float sc = gamma[tid] / sqrtf(var + 1e-5f);
            stl[tid] = sc;
            stl[64 + tid] = fmaf(-mu, sc, beta[tid]);
        }
        __syncthreads();
    }

    if (CIN == 64) {
        const float4* __restrict__ in4 = (const float4*)in + (size_t)g * NN * 64;
        int c4 = lane & 15, bi = lane >> 4;
        float4 sv = {1.f,1.f,1.f,1.f}, tv = {0.f,0.f,0.f,0.f};
        if (ACT) { sv = ((const float4*)stl)[c4]; tv = ((const float4*)(stl + 64))[c4]; }
#pragma unroll
        for (int i = 0; i < 4; ++i) {
            int r = base + i;
            float4 a = {0.f,0.f,0.f,0.f};
            if (r < NN) {
                float d = dinv[r];
                float dd = d * d;
                float4 v = actv<ACT>(in4[(size_t)r * 64 + lane], sv, tv);
                a.x = dd * v.x; a.y = dd * v.y; a.z = dd * v.z; a.w = dd * v.w;
                int p0 = rowptr[r], p1 = rowptr[r + 1];   // both multiples of 4
                for (int e = p0; e < p1; e += 4) {
                    int4   cc = *(const int4*)(csr_col + e);
                    float4 ww = *(const float4*)(csr_nv + e);
                    float4 v0 = in4[(size_t)cc.x * 64 + lane];
                    float4 v1 = in4[(size_t)cc.y * 64 + lane];
                    float4 v2 = in4[(size_t)cc.z * 64 + lane];
                    float4 v3 = in4[(size_t)cc.w * 64 + lane];
                    fma4(a, ww.x, actv<ACT>(v0, sv, tv));
                    fma4(a, ww.y, actv<ACT>(v1, sv, tv));
                    fma4(a, ww.z, actv<ACT>(v2, sv, tv));
                    fma4(a, ww.w, actv<ACT>(v3, sv, tv));
                }
            }
            *(float4*)(Aw + (i * 4 + bi) * ALS + c4 * 4) = a;
        }
    } else {
        const float* __restrict__ inr = in + (size_t)g * NN * 64;   // row = 64 floats
#pragma unroll
        for (int i = 0; i < 4; ++i) {
            int r = base + i;
            float a = 0.f;
            if (r < NN) {
                float d = dinv[r];
                a = d * d * inr[(size_t)r * 64 + lane];
                int p0 = rowptr[r], p1 = rowptr[r + 1];
                for (int e = p0; e < p1; e += 4) {
                    int4   cc = *(const int4*)(csr_col + e);
                    float4 ww = *(const float4*)(csr_nv + e);
                    float v0 = inr[(size_t)cc.x * 64 + lane];
                    float v1 = inr[(size_t)cc.y * 64 + lane];
                    float v2 = inr[(size_t)cc.z * 64 + lane];
                    float v3 = inr[(size_t)cc.w * 64 + lane];
                    a = fmaf(ww.x, v0, a);
                    a = fmaf(ww.y, v1, a);
                    a = fmaf(ww.z, v2, a);
                    a = fmaf(ww.w, v3, a);
                }
            }
            Aw[(i * 4 + (lane >> 4)) * ALS + (lane & 15)] = a;
        }
    }
    __syncthreads();

    int colq = lane & 15, rowq = lane >> 4;
    int node = base + rowq;

    if (!SCORE) {
        // ---- stage 2: per-wave GEMM; thread -> (node rowq, colq) [R9 shape] ----
        const float4* __restrict__ W4 = (const float4*)W;
        float4 bb = ((const float4*)bias)[colq];
        float4 o[4];
#pragma unroll
        for (int i = 0; i < 4; ++i) o[i] = bb;
#pragma unroll 8
        for (int k = 0; k < CIN; ++k) {
            float4 w4 = W4[k * 16 + colq];
#pragma unroll
            for (int i = 0; i < 4; ++i) {
                float a = Aw[(rowq * 4 + i) * ALS + k];
                fma4(o[i], a, w4);
            }
        }
        if (node < NN) {
            float4* __restrict__ op = (float4*)(out + ((size_t)g * NN + node) * 256);
#pragma unroll
            for (int i = 0; i < 4; ++i) op[i * 16 + colq] = o[i];
        }

        if (STATS) {
            float4 s4 = {0,0,0,0}, q4 = {0,0,0,0};
            if (node < NN) {
#pragma unroll
                for (int i = 0; i < 4; ++i) {
                    s4.x += o[i].x; s4.y += o[i].y; s4.z += o[i].z; s4.w += o[i].w;
                    q4.x = fmaf(o[i].x, o[i].x, q4.x); q4.y = fmaf(o[i].y, o[i].y, q4.y);
                    q4.z = fmaf(o[i].z, o[i].z, q4.z); q4.w = fmaf(o[i].w, o[i].w, q4.w);
                }
            }
            s4.x += __shfl_xor(s4.x, 16); s4.y += __shfl_xor(s4.y, 16);
            s4.z += __shfl_xor(s4.z, 16); s4.w += __shfl_xor(s4.w, 16);
            q4.x += __shfl_xor(q4.x, 16); q4.y += __shfl_xor(q4.y, 16);
            q4.z += __shfl_xor(q4.z, 16); q4.w += __shfl_xor(q4.w, 16);
            s4.x += __shfl_xor(s4.x, 32); s4.y += __shfl_xor(s4.y, 32);
            s4.z += __shfl_xor(s4.z, 32); s4.w += __shfl_xor(s4.w, 32);
            q4.x += __shfl_xor(q4.x, 32); q4.y += __shfl_xor(q4.y, 32);
            q4.z += __shfl_xor(q4.z, 32); q4.w += __shfl_xor(q4.w, 32);
            __syncthreads();   // As free for reuse
            if (lane < 16) {
                float* S = As + wid * 128;
                *(float4*)(S + lane * 8) = s4;
                *(float4*)(S + lane * 8 + 4) = q4;
            }
            __syncthreads();
            if (tid < 64) {
                int cq = tid >> 2, comp = tid & 3;
                float s = 0.f, q = 0.f;
#pragma unroll
                for (int w = 0; w < 4; ++w) {
                    s += As[w * 128 + cq * 8 + comp];
                    q += As[w * 128 + cq * 8 + 4 + comp];
                }
                float* sl = stats + (blockIdx.x & (NSLOT - 1)) * 128;
                atomicAdd(&sl[tid], s);
                atomicAdd(&sl[64 + tid], q);
            }
        }
    } else {
        // ---- SCORE mode: write agg from LDS + compact relu'd score (ch 63) ----
        if (node < NN) {
            float4* __restrict__ op = (float4*)(out + ((size_t)g * NN + node) * 256);
#pragma unroll
            for (int i = 0; i < 4; ++i)
                op[i * 16 + colq] = *(const float4*)(Aw + (rowq * 4 + i) * ALS + colq * 4);
        }
        if (lane < 16) {
            int nd = base + (lane >> 2);
            if (nd < NN) {
                float s = bias[63];
                const float* Ar = Aw + lane * ALS;   // row lane = (node lane>>2, bi lane&3)
#pragma unroll 8
                for (int k = 0; k < 64; ++k)
                    s = fmaf(Ar[k], W[k * 64 + 63], s);
                score[((size_t)g * NN + nd) * 4 + (lane & 3)] = fmaxf(s, 0.f);
            }
        }
    }
}

// compute BOTH layers' scale/shift for k_gather (layers compute their own inline)
__global__ void k_bnfin(const float* __restrict__ stats,
                        const float* __restrict__ g0, const float* __restrict__ be0,
                        const float* __restrict__ g1, const float* __restrict__ be1,
                        float* st) {
    int tid = threadIdx.x;  // 128
    int c = tid & 63, layer = tid >> 6;
    const float* sb = stats + layer * NSLOT * 128;
    float su = 0.f, qu = 0.f;
#pragma unroll
    for (int s = 0; s < NSLOT; ++s) {
        su += sb[s * 128 + c];
        qu += sb[s * 128 + 64 + c];
    }
    const float inv = 1.0f / (float)(NB * NN);
    float mu = su * inv;
    float var = qu * inv - mu * mu;
    float g = layer ? g1[c] : g0[c];
    float be = layer ? be1[c] : be0[c];
    float sc = g / sqrtf(var + 1e-5f);
    st[layer * 128 + c] = sc;
    st[layer * 128 + 64 + c] = fmaf(-mu, sc, be);
}

// ---------------- global_sort_pool: register top-30 on compact score array ----
__global__ __launch_bounds__(1024) void k_toppool(const float* __restrict__ sc, int* order) {
    __shared__ unsigned long long wbest[16];
    __shared__ unsigned long long winner;
    int b = blockIdx.x, tid = threadIdx.x;
    int g = b >> 2, bi = b & 3;
    int lane = tid & 63, wid = tid >> 6;
    unsigned long long key[5];
#pragma unroll
    for (int j = 0; j < 5; ++j) {
        int n = tid + j * 1024;
        unsigned long long k = 0;
        if (n < NN) {
            float v = sc[((size_t)g * NN + n) * GB + bi];   // already relu'd
            k = ((unsigned long long)__float_as_uint(v) << 32) | (unsigned int)(NN - n);
        }
        key[j] = k;
    }
    for (int k = 0; k < KPOOL; ++k) {
        unsigned long long best = key[0];
#pragma unroll
        for (int j = 1; j < 5; ++j) best = (key[j] > best) ? key[j] : best;
#pragma unroll
        for (int off = 1; off < 64; off <<= 1) {
            unsigned long long o = __shfl_xor(best, off);
            best = (o > best) ? o : best;
        }
        if (lane == 0) wbest[wid] = best;
        __syncthreads();
        if (tid == 0) {
            unsigned long long w = wbest[0];
#pragma unroll
            for (int i = 1; i < 16; ++i) w = (wbest[i] > w) ? wbest[i] : w;
            winner = w;
            order[b * KPOOL + k] = NN - (int)(w & 0xFFFFFFFFu);
        }
        __syncthreads();
        int n = NN - (int)(winner & 0xFFFFFFFFu);
        if ((n & 1023) == tid) key[n >> 10] = 0;   // remove winner (owner thread)
    }
}

// ---------------- gather selected nodes into flat (B, 6241) ----------------
// h3 branch does the DEFERRED layer-2 GEMM (64 wide) from agg — only 960
// (b,node) pairs ever need it.
__global__ void k_gather(const float* __restrict__ xt, const float* __restrict__ h1,
                         const float* __restrict__ h2, const float* __restrict__ agg,
                         const float* __restrict__ W2, const float* __restrict__ b2,
                         const float* __restrict__ st, const float* __restrict__ age,
                         const int* __restrict__ order, float* __restrict__ flat) {
    int bk = blockIdx.x;
    int b = bk / KPOOL, k = bk % KPOOL;
    int n = order[bk];
    int g = b >> 2, bi = b & 3;
    size_t node = (size_t)g * NN + n;
    int f = threadIdx.x;
    float val = 0.f;
    if (f < DIN) {
        val = xt[(node * GB + bi) * DIN + f];
    } else if (f < DIN + CH) {
        int c = f - DIN;
        val = fmaxf(fmaf(h1[(node * GB + bi) * CH + c], st[c], st[64 + c]), 0.f);
    } else if (f < DIN + 2 * CH) {
        int c = f - DIN - CH;
        val = fmaxf(fmaf(h2[(node * GB + bi) * CH + c], st[128 + c], st[192 + c]), 0.f);
    } else if (f < FTOT) {
        int c = f - DIN - 2 * CH;
        const float* __restrict__ Ar = agg + (node * GB + bi) * CH;
        float s = b2[c];
#pragma unroll 8
        for (int kk = 0; kk < 64; ++kk)
            s = fmaf(Ar[kk], W2[kk * 64 + c], s);   // Ar broadcast, W2 coalesced
        val = fmaxf(s, 0.f);
    }
    if (f < FTOT) flat[(size_t)b * FLATW + k * FTOT + f] = val;
    if (bk == 0 && f >= FTOT && f < FTOT + NB)
        flat[(size_t)(f - FTOT) * FLATW + (FLATW - 1)] = age[f - FTOT];
}

// ---------------- MLP head layer 1: hm += flat @ mW0 (k-split, atomics) ----------------
__global__ void k_head1(const float* __restrict__ flat, const float* __restrict__ mW0,
                        float* hm) {
    int tid = threadIdx.x;
    int j4 = (tid & 31) * 4;       // 32 groups * 4 = 128 cols
    int b0 = (tid >> 5) * 4;       // 8 groups * 4 = 32 rows
    int kbase = blockIdx.x * 64;
    float acc[4][4];
#pragma unroll
    for (int i = 0; i < 4; i++)
#pragma unroll
        for (int jj = 0; jj < 4; jj++) acc[i][jj] = 0.f;
    int kend = FLATW - kbase; if (kend > 64) kend = 64;
    for (int kk = 0; kk < kend; ++kk) {
        int k = kbase + kk;
        float4 w = *(const float4*)(mW0 + (size_t)k * NH + j4);
#pragma unroll
        for (int i = 0; i < 4; i++) {
            float fv = flat[(size_t)(b0 + i) * FLATW + k];
            acc[i][0] = fmaf(fv, w.x, acc[i][0]);
            acc[i][1] = fmaf(fv, w.y, acc[i][1]);
            acc[i][2] = fmaf(fv, w.z, acc[i][2]);
            acc[i][3] = fmaf(fv, w.w, acc[i][3]);
        }
    }
#pragma unroll
    for (int i = 0; i < 4; i++)
#pragma unroll
        for (int jj = 0; jj < 4; jj++)
            atomicAdd(&hm[(size_t)(b0 + i) * NH + j4 + jj], acc[i][jj]);
}

// ---------------- head layer 2 + log_softmax ----------------
__global__ void k_head2(const float* __restrict__ hm, const float* __restrict__ mb0,
                        const float* __restrict__ mW1, const float* __restrict__ mb1,
                        float* __restrict__ out) {
    __shared__ float vals[64];
    int tid = threadIdx.x;  // 64 = 32 b * 2 o
    int b = tid >> 1, o = tid & 1;
    float acc = mb1[o];
    for (int j = 0; j < NH; ++j) {
        float hv = fmaxf(hm[b * NH + j] + mb0[j], 0.f);
        acc = fmaf(hv, mW1[j * 2 + o], acc);
    }
    vals[tid] = acc;
    __syncthreads();
    float v0 = vals[b * 2], v1 = vals[b * 2 + 1];
    float m = fmaxf(v0, v1);
    float lse = m + logf(expf(v0 - m) + expf(v1 - m));
    out[tid] = acc - lse;
}

extern "C" void kernel_launch(void* const* d_in, const int* in_sizes, int n_in,
                              void* d_out, int out_size, void* d_ws, size_t ws_size,
                              hipStream_t stream) {
    const float* x    = (const float*)d_in[0];
    const float* age  = (const float*)d_in[1];
    const float* attr = (const float*)d_in[2];
    const float* W0   = (const float*)d_in[3];
    const float* b0   = (const float*)d_in[4];
    const float* W1   = (const float*)d_in[5];
    const float* b1   = (const float*)d_in[6];
    const float* W2   = (const float*)d_in[7];
    const float* b2   = (const float*)d_in[8];
    const float* g0   = (const float*)d_in[9];
    const float* be0  = (const float*)d_in[10];
    const float* g1   = (const float*)d_in[11];
    const float* be1  = (const float*)d_in[12];
    const float* mW0  = (const float*)d_in[13];
    const float* mb0  = (const float*)d_in[14];
    const float* mW1  = (const float*)d_in[15];
    const float* mb1  = (const float*)d_in[16];
    const int* erow   = (const int*)d_in[17];
    const int* ecol   = (const int*)d_in[18];
    float* out = (float*)d_out;

    // workspace layout (floats); all float4-aligned
    float* ws     = (float*)d_ws;
    float* deg    = ws;                                  // 5008
    float* dinv   = deg + 5008;                          // 5008
    int*   counts = (int*)(dinv + 5008);                 // 5008
    int*   rowptr = counts + 5008;                       // 5008
    int*   cursor = rowptr + 5008;                       // 5008
    int*   csr_col= cursor + 5008;                       // NEPAD
    float* csr_nv = (float*)(csr_col + NEPAD);           // NEPAD
    float* stats  = csr_nv + NEPAD;                      // 2*32*128 = 8192
    float* st     = stats + 2 * NSLOT * 128;             // 256 (s0,t0,s1,t1)
    float* sc     = st + 256;                            // NB*NN = 160000 (scores)
    int*   order  = (int*)(sc + NB * NN);                // 960
    float* flat   = (float*)(order + 960);               // 32*6241
    float* hm     = flat + (size_t)NB * FLATW;           // 4096
    float* xt     = hm + 4096;                           // (G8,N,4,16)
    float* h1     = xt + (size_t)NB * NN * DIN;          // (G8,N,4,64) each
    float* h2     = h1 + (size_t)NB * NN * CH;
    float* agg    = h2 + (size_t)NB * NN * CH;           // layer-2 aggregate (pre-GEMM)

    // graph build
    k_init<<<32, 256, 0, stream>>>(deg, counts, stats, hm);
    k_edgetr<<<NEB + (NB * NN + 255) / 256, 256, 0, stream>>>(attr, erow, deg, counts, x, xt);
    k_scan<<<1, 1024, 0, stream>>>(counts, deg, rowptr, cursor, dinv);
    k_build<<<(NE + NN + 255) / 256, 256, 0, stream>>>(erow, ecol, attr, dinv, counts, rowptr, cursor, csr_col, csr_nv);

    const int NBLK = ((NN + NPB - 1) / NPB) * NG;   // 313 * 8
    // fused layers (gather + per-wave GEMM + slot-spread BN stats + inline BN-in)
    k_layer<16, 0, 1, 0><<<NBLK, 256, 0, stream>>>(xt, nullptr, nullptr, nullptr, W0, b0, rowptr, csr_col, csr_nv, dinv, h1, stats, nullptr);
    k_layer<64, 1, 1, 0><<<NBLK, 256, 0, stream>>>(h1, stats, g0, be0, W1, b1, rowptr, csr_col, csr_nv, dinv, h2, stats + NSLOT * 128, nullptr);
    k_layer<64, 1, 0, 1><<<NBLK, 256, 0, stream>>>(h2, stats + NSLOT * 128, g1, be1, W2, b2, rowptr, csr_col, csr_nv, dinv, agg, nullptr, sc);

    // bn scale/shift for gather + sort-pool + gather (deferred GEMM) + head
    k_bnfin<<<1, 128, 0, stream>>>(stats, g0, be0, g1, be1, st);
    k_toppool<<<NB, 1024, 0, stream>>>(sc, order);
    k_gather<<<NB * KPOOL, 256, 0, stream>>>(xt, h1, h2, agg, W2, b2, st, age, order, flat);
    k_head1<<<(FLATW + 63) / 64, 256, 0, stream>>>(flat, mW0, hm);
    k_head2<<<1, 64, 0, stream>>>(hm, mb0, mW1, mb1, out);
}

// Round 17
// 365.894 us; speedup vs baseline: 1.2849x; 1.0093x over previous
//
#include <hip/hip_runtime.h>
#include <math.h>

// Problem constants (from reference setup_inputs)
#define NN    5000      // nodes
#define NE    80000     // edges
#define NB    32        // batch
#define DIN   16        // input feat
#define CH    64        // conv channels
#define KPOOL 30
#define FTOT  208      // 16 + 3*64
#define FLATW 6241     // KPOOL*FTOT + 1
#define NH    128      // MLP hidden
#define NG    8        // batch groups (one per XCD; G>8 useless: 2 groups share an XCD — R14)
#define GB    4        // batches per group
#define NPB   16       // nodes per block (4 per wave)
#define NEPAD (NE + 4 * NN)   // CSR rows padded to multiple of 4
#define NSLOT 32       // stats atomic-spread slots (contention 2504 -> ~78)

// Feature tensors use BATCH-SPLIT NODE-MAJOR layout: (G=8, N, 4, C).

// ---------------- setup kernels ----------------

__global__ void k_init(float* deg, int* counts, float* stats, float* hm) {
    int i = blockIdx.x * 256 + threadIdx.x;
    if (i < NN) { deg[i] = 1.0f; counts[i] = 0; }   // deg starts at self-loop value 1
    if (i < 2 * NSLOT * 128) stats[i] = 0.0f;       // [2 layers][32 slots][128]
    if (i < 4096) hm[i] = 0.0f;
}

// merged: edge-degree atomics (blocks 0..312) + x transpose (blocks 313..937)
#define NEB 313
__global__ void k_edgetr(const float* __restrict__ attr, const int* __restrict__ erow,
                         float* deg, int* counts,
                         const float* __restrict__ x, float* __restrict__ xt) {
    if (blockIdx.x < NEB) {
        int e = blockIdx.x * 256 + threadIdx.x;
        if (e < NE) {
            int r = erow[e];
            atomicAdd(&deg[r], attr[e]);
            atomicAdd(&counts[r], 1);
        }
    } else {
        int idx = (blockIdx.x - NEB) * 256 + threadIdx.x;
        if (idx >= NB * NN) return;
        int b = idx / NN, n = idx % NN;
        int g = b >> 2, bi = b & 3;
        const float4* src = (const float4*)(x + (size_t)idx * DIN);
        float4* dst = (float4*)(xt + (((size_t)g * NN + n) * GB + bi) * DIN);
        dst[0] = src[0]; dst[1] = src[1]; dst[2] = src[2]; dst[3] = src[3];
    }
}

// scan PADDED counts (rounded up to mult of 4) + dinv; wave-shuffle scan
__global__ __launch_bounds__(1024) void k_scan(const int* __restrict__ counts,
                                               const float* __restrict__ deg,
                                               int* rowptr, int* cursor, float* dinv) {
    __shared__ int wsum[16], woff[16];
    __shared__ int carry_sh;
    int t = threadIdx.x;
    int lane = t & 63, wid = t >> 6;
    if (t == 0) carry_sh = 0;
    __syncthreads();
    for (int base = 0; base < NN; base += 1024) {
        int carry = carry_sh;
        int i = base + t;
        int v = 0;
        if (i < NN) {
            v = (counts[i] + 3) & ~3;
            dinv[i] = 1.0f / sqrtf(deg[i]);   // deg >= 1 always
        }
        int s = v;
#pragma unroll
        for (int off = 1; off < 64; off <<= 1) {
            int o = __shfl_up(s, off);
            if (lane >= off) s += o;
        }
        if (lane == 63) wsum[wid] = s;
        __syncthreads();
        if (t < 16) {
            int w = wsum[t];
#pragma unroll
            for (int off = 1; off < 16; off <<= 1) {
                int o = __shfl_up(w, off);
                if (t >= off) w += o;
            }
            woff[t] = w;
        }
        __syncthreads();
        int inc = s + (wid > 0 ? woff[wid - 1] : 0) + carry;
        if (i < NN) {
            rowptr[i + 1] = inc;
            cursor[i] = inc - v;
        }
        if (t == 1023) carry_sh = carry + woff[15];
        __syncthreads();
    }
    if (t == 0) rowptr[0] = 0;
}

// merged: CSR scatter (t < NE) + zero-weight pad fill (t-NE < NN); disjoint slots
__global__ void k_build(const int* __restrict__ erow, const int* __restrict__ ecol,
                        const float* __restrict__ attr, const float* __restrict__ dinv,
                        const int* __restrict__ counts, const int* __restrict__ rowptr,
                        int* cursor, int* csr_col, float* csr_nv) {
    int t = blockIdx.x * 256 + threadIdx.x;
    if (t < NE) {
        int r = erow[t], c = ecol[t];
        int pos = atomicAdd(&cursor[r], 1);
        csr_col[pos] = c;
        csr_nv[pos] = dinv[r] * attr[t] * dinv[c];
    } else if (t - NE < NN) {
        int i = t - NE;
        int cnt = counts[i];
        int pcnt = (cnt + 3) & ~3;
        int base = rowptr[i + 1] - pcnt;
        for (int p = base + cnt; p < base + pcnt; ++p) { csr_col[p] = i; csr_nv[p] = 0.0f; }
    }
}

// ---------------- helpers ----------------
template<int ACT>
__device__ __forceinline__ float4 actv(float4 v, float4 s, float4 t) {
    if (ACT) {
        v.x = fmaxf(fmaf(v.x, s.x, t.x), 0.f);
        v.y = fmaxf(fmaf(v.y, s.y, t.y), 0.f);
        v.z = fmaxf(fmaf(v.z, s.z, t.z), 0.f);
        v.w = fmaxf(fmaf(v.w, s.w, t.w), 0.f);
    }
    return v;
}
__device__ __forceinline__ void fma4(float4& a, float w, float4 v) {
    a.x = fmaf(w, v.x, a.x); a.y = fmaf(w, v.y, a.y);
    a.z = fmaf(w, v.z, a.z); a.w = fmaf(w, v.w, a.w);
}

// ---------------- fused GCN layer ----------------
// Block = (16 nodes, group g). Stage 0 (ACT): BN scale/shift from slot stats
// into LDS. Stage 1 (CIN=64): wave's 4 nodes processed as 2 INTERLEAVED PAIRS
// — one merged edge loop per pair; shorter row's bundles get col sanitized to
// 0 and weight 0 (R16 crash: clamped metadata read 0xAA-poisoned CSR tail ->
// wild feature address; zero-weight loads still need VALID addresses).
// Stage 2 (SCORE=0): R9 per-wave GEMM (W float4 global + scalar LDS A — do
// NOT vectorize A reads, R10 regression). Stage 2 (SCORE=1): write agg +
// compact score only; full GEMM deferred to k_gather. STATS: slot-spread
// atomic BN epilogue.
template<int CIN, int ACT, int STATS, int SCORE>
__global__ __launch_bounds__(256) void k_layer(
        const float* __restrict__ in, const float* __restrict__ bnstats,
        const float* __restrict__ gamma, const float* __restrict__ beta,
        const float* __restrict__ W, const float* __restrict__ bias,
        const int* __restrict__ rowptr, const int* __restrict__ csr_col,
        const float* __restrict__ csr_nv, const float* __restrict__ dinv,
        float* __restrict__ out, float* __restrict__ stats,
        float* __restrict__ score) {
    constexpr int ALS = (CIN == 64) ? 68 : 20;
    __shared__ float As[4 * 16 * ALS];
    __shared__ float stl[ACT ? 128 : 4];
    int tid = threadIdx.x;
    int wid = tid >> 6, lane = tid & 63;
    int g = blockIdx.x & 7;                      // XCD round-robin
    int nb = (blockIdx.x >> 3) * NPB;
    int base = nb + wid * 4;
    float* Aw = As + wid * 16 * ALS;

    if (ACT) {
        if (tid < 64) {
            float su = 0.f, qu = 0.f;
#pragma unroll
            for (int s = 0; s < NSLOT; ++s) {
                su += bnstats[s * 128 + tid];
                qu += bnstats[s * 128 + 64 + tid];
            }
            const float inv = 1.0f / (float)(NB * NN);
            float mu = su * inv;
            float var = qu * inv - mu * mu;
            float sc = gamma[tid] / sqrtf(var + 1e-5f);
            stl[tid] = sc;
            stl[64 + tid] = fmaf(-mu, sc, beta[tid]);
        }
        __syncthreads();
    }

    if (CIN == 64) {
        const float4* __restrict__ in4 = (const float4*)in + (size_t)g * NN * 64;
        int c4 = lane & 15, bi = lane >> 4;
        float4 sv = {1.f,1.f,1.f,1.f}, tv = {0.f,0.f,0.f,0.f};
        if (ACT) { sv = ((const float4*)stl)[c4]; tv = ((const float4*)(stl + 64))[c4]; }
#pragma unroll
        for (int pr = 0; pr < 2; ++pr) {
            int r0 = base + pr * 2;
            int r1 = r0 + 1;
            bool vn0 = r0 < NN, vn1 = r1 < NN;
            int rc0 = vn0 ? r0 : 0, rc1 = vn1 ? r1 : 0;
            float dd0 = dinv[rc0]; dd0 *= dd0;
            float dd1 = dinv[rc1]; dd1 *= dd1;
            float4 a0 = {0.f,0.f,0.f,0.f}, a1 = {0.f,0.f,0.f,0.f};
            {
                float4 v0 = actv<ACT>(in4[(size_t)rc0 * 64 + lane], sv, tv);
                float4 v1 = actv<ACT>(in4[(size_t)rc1 * 64 + lane], sv, tv);
                if (vn0) { a0.x = dd0 * v0.x; a0.y = dd0 * v0.y; a0.z = dd0 * v0.z; a0.w = dd0 * v0.w; }
                if (vn1) { a1.x = dd1 * v1.x; a1.y = dd1 * v1.y; a1.z = dd1 * v1.z; a1.w = dd1 * v1.w; }
            }
            int p0a = rowptr[rc0], na = vn0 ? (rowptr[rc0 + 1] - p0a) >> 2 : 0;
            int p0b = rowptr[rc1], nbv = vn1 ? (rowptr[rc1 + 1] - p0b) >> 2 : 0;
            int mx = max(na, nbv);
            for (int bb = 0; bb < mx; ++bb) {
                int ea = min(p0a + 4 * bb, NEPAD - 4);
                int eb = min(p0b + 4 * bb, NEPAD - 4);
                bool va = bb < na, vb = bb < nbv;
                int4   ca = *(const int4*)(csr_col + ea);
                float4 wa = *(const float4*)(csr_nv + ea);
                int4   cb = *(const int4*)(csr_col + eb);
                float4 wb = *(const float4*)(csr_nv + eb);
                if (!va) { wa.x = 0.f; wa.y = 0.f; wa.z = 0.f; wa.w = 0.f;
                           ca.x = 0; ca.y = 0; ca.z = 0; ca.w = 0; }   // CSR tail is 0xAA-poisoned
                if (!vb) { wb.x = 0.f; wb.y = 0.f; wb.z = 0.f; wb.w = 0.f;
                           cb.x = 0; cb.y = 0; cb.z = 0; cb.w = 0; }
                float4 u0 = in4[(size_t)ca.x * 64 + lane];
                float4 u1 = in4[(size_t)ca.y * 64 + lane];
                float4 u2 = in4[(size_t)ca.z * 64 + lane];
                float4 u3 = in4[(size_t)ca.w * 64 + lane];
                float4 t0 = in4[(size_t)cb.x * 64 + lane];
                float4 t1 = in4[(size_t)cb.y * 64 + lane];
                float4 t2 = in4[(size_t)cb.z * 64 + lane];
                float4 t3 = in4[(size_t)cb.w * 64 + lane];
                fma4(a0, wa.x, actv<ACT>(u0, sv, tv));
                fma4(a0, wa.y, actv<ACT>(u1, sv, tv));
                fma4(a0, wa.z, actv<ACT>(u2, sv, tv));
                fma4(a0, wa.w, actv<ACT>(u3, sv, tv));
                fma4(a1, wb.x, actv<ACT>(t0, sv, tv));
                fma4(a1, wb.y, actv<ACT>(t1, sv, tv));
                fma4(a1, wb.z, actv<ACT>(t2, sv, tv));
                fma4(a1, wb.w, actv<ACT>(t3, sv, tv));
            }
            *(float4*)(Aw + ((pr * 2 + 0) * 4 + bi) * ALS + c4 * 4) = a0;
            *(float4*)(Aw + ((pr * 2 + 1) * 4 + bi) * ALS + c4 * 4) = a1;
        }
    } else {
        const float* __restrict__ inr = in + (size_t)g * NN * 64;   // row = 64 floats
#pragma unroll
        for (int i = 0; i < 4; ++i) {
            int r = base + i;
            float a = 0.f;
            if (r < NN) {
                float d = dinv[r];
                a = d * d * inr[(size_t)r * 64 + lane];
                int p0 = rowptr[r], p1 = rowptr[r + 1];
                for (int e = p0; e < p1; e += 4) {
                    int4   cc = *(const int4*)(csr_col + e);
                    float4 ww = *(const float4*)(csr_nv + e);
                    float v0 = inr[(size_t)cc.x * 64 + lane];
                    float v1 = inr[(size_t)cc.y * 64 + lane];
                    float v2 = inr[(size_t)cc.z * 64 + lane];
                    float v3 = inr[(size_t)cc.w * 64 + lane];
                    a = fmaf(ww.x, v0, a);
                    a = fmaf(ww.y, v1, a);
                    a = fmaf(ww.z, v2, a);
                    a = fmaf(ww.w, v3, a);
                }
            }
            Aw[(i * 4 + (lane >> 4)) * ALS + (lane & 15)] = a;
        }
    }
    __syncthreads();

    int colq = lane & 15, rowq = lane >> 4;
    int node = base + rowq;

    if (!SCORE) {
        // ---- stage 2: per-wave GEMM; thread -> (node rowq, colq) [R9 shape] ----
        const float4* __restrict__ W4 = (const float4*)W;
        float4 bb = ((const float4*)bias)[colq];
        float4 o[4];
#pragma unroll
        for (int i = 0; i < 4; ++i) o[i] = bb;
#pragma unroll 8
        for (int k = 0; k < CIN; ++k) {
            float4 w4 = W4[k * 16 + colq];
#pragma unroll
            for (int i = 0; i < 4; ++i) {
                float a = Aw[(rowq * 4 + i) * ALS + k];
                fma4(o[i], a, w4);
            }
        }
        if (node < NN) {
            float4* __restrict__ op = (float4*)(out + ((size_t)g * NN + node) * 256);
#pragma unroll
            for (int i = 0; i < 4; ++i) op[i * 16 + colq] = o[i];
        }

        if (STATS) {
            float4 s4 = {0,0,0,0}, q4 = {0,0,0,0};
            if (node < NN) {
#pragma unroll
                for (int i = 0; i < 4; ++i) {
                    s4.x += o[i].x; s4.y += o[i].y; s4.z += o[i].z; s4.w += o[i].w;
                    q4.x = fmaf(o[i].x, o[i].x, q4.x); q4.y = fmaf(o[i].y, o[i].y, q4.y);
                    q4.z = fmaf(o[i].z, o[i].z, q4.z); q4.w = fmaf(o[i].w, o[i].w, q4.w);
                }
            }
            s4.x += __shfl_xor(s4.x, 16); s4.y += __shfl_xor(s4.y, 16);
            s4.z += __shfl_xor(s4.z, 16); s4.w += __shfl_xor(s4.w, 16);
            q4.x += __shfl_xor(q4.x, 16); q4.y += __shfl_xor(q4.y, 16);
            q4.z += __shfl_xor(q4.z, 16); q4.w += __shfl_xor(q4.w, 16);
            s4.x += __shfl_xor(s4.x, 32); s4.y += __shfl_xor(s4.y, 32);
            s4.z += __shfl_xor(s4.z, 32); s4.w += __shfl_xor(s4.w, 32);
            q4.x += __shfl_xor(q4.x, 32); q4.y += __shfl_xor(q4.y, 32);
            q4.z += __shfl_xor(q4.z, 32); q4.w += __shfl_xor(q4.w, 32);
            __syncthreads();   // As free for reuse
            if (lane < 16) {
                float* S = As + wid * 128;
                *(float4*)(S + lane * 8) = s4;
                *(float4*)(S + lane * 8 + 4) = q4;
            }
            __syncthreads();
            if (tid < 64) {
                int cq = tid >> 2, comp = tid & 3;
                float s = 0.f, q = 0.f;
#pragma unroll
                for (int w = 0; w < 4; ++w) {
                    s += As[w * 128 + cq * 8 + comp];
                    q += As[w * 128 + cq * 8 + 4 + comp];
                }
                float* sl = stats + (blockIdx.x & (NSLOT - 1)) * 128;
                atomicAdd(&sl[tid], s);
                atomicAdd(&sl[64 + tid], q);
            }
        }
    } else {
        // ---- SCORE mode: write agg from LDS + compact relu'd score (ch 63) ----
        if (node < NN) {
            float4* __restrict__ op = (float4*)(out + ((size_t)g * NN + node) * 256);
#pragma unroll
            for (int i = 0; i < 4; ++i)
                op[i * 16 + colq] = *(const float4*)(Aw + (rowq * 4 + i) * ALS + colq * 4);
        }
        if (lane < 16) {
            int nd = base + (lane >> 2);
            if (nd < NN) {
                float s = bias[63];
                const float* Ar = Aw + lane * ALS;   // row lane = (node lane>>2, bi lane&3)
#pragma unroll 8
                for (int k = 0; k < 64; ++k)
                    s = fmaf(Ar[k], W[k * 64 + 63], s);
                score[((size_t)g * NN + nd) * 4 + (lane & 3)] = fmaxf(s, 0.f);
            }
        }
    }
}

// compute BOTH layers' scale/shift for k_gather (layers compute their own inline)
__global__ void k_bnfin(const float* __restrict__ stats,
                        const float* __restrict__ g0, const float* __restrict__ be0,
                        const float* __restrict__ g1, const float* __restrict__ be1,
                        float* st) {
    int tid = threadIdx.x;  // 128
    int c = tid & 63, layer = tid >> 6;
    const float* sb = stats + layer * NSLOT * 128;
    float su = 0.f, qu = 0.f;
#pragma unroll
    for (int s = 0; s < NSLOT; ++s) {
        su += sb[s * 128 + c];
        qu += sb[s * 128 + 64 + c];
    }
    const float inv = 1.0f / (float)(NB * NN);
    float mu = su * inv;
    float var = qu * inv - mu * mu;
    float g = layer ? g1[c] : g0[c];
    float be = layer ? be1[c] : be0[c];
    float sc = g / sqrtf(var + 1e-5f);
    st[layer * 128 + c] = sc;
    st[layer * 128 + 64 + c] = fmaf(-mu, sc, be);
}

// ---------------- global_sort_pool: register top-30 on compact score array ----
__global__ __launch_bounds__(1024) void k_toppool(const float* __restrict__ sc, int* order) {
    __shared__ unsigned long long wbest[16];
    __shared__ unsigned long long winner;
    int b = blockIdx.x, tid = threadIdx.x;
    int g = b >> 2, bi = b & 3;
    int lane = tid & 63, wid = tid >> 6;
    unsigned long long key[5];
#pragma unroll
    for (int j = 0; j < 5; ++j) {
        int n = tid + j * 1024;
        unsigned long long k = 0;
        if (n < NN) {
            float v = sc[((size_t)g * NN + n) * GB + bi];   // already relu'd
            k = ((unsigned long long)__float_as_uint(v) << 32) | (unsigned int)(NN - n);
        }
        key[j] = k;
    }
    for (int k = 0; k < KPOOL; ++k) {
        unsigned long long best = key[0];
#pragma unroll
        for (int j = 1; j < 5; ++j) best = (key[j] > best) ? key[j] : best;
#pragma unroll
        for (int off = 1; off < 64; off <<= 1) {
            unsigned long long o = __shfl_xor(best, off);
            best = (o > best) ? o : best;
        }
        if (lane == 0) wbest[wid] = best;
        __syncthreads();
        if (tid == 0) {
            unsigned long long w = wbest[0];
#pragma unroll
            for (int i = 1; i < 16; ++i) w = (wbest[i] > w) ? wbest[i] : w;
            winner = w;
            order[b * KPOOL + k] = NN - (int)(w & 0xFFFFFFFFu);
        }
        __syncthreads();
        int n = NN - (int)(winner & 0xFFFFFFFFu);
        if ((n & 1023) == tid) key[n >> 10] = 0;   // remove winner (owner thread)
    }
}

// ---------------- gather selected nodes into flat (B, 6241) ----------------
// h3 branch does the DEFERRED layer-2 GEMM (64 wide) from agg — only 960
// (b,node) pairs ever need it.
__global__ void k_gather(const float* __restrict__ xt, const float* __restrict__ h1,
                         const float* __restrict__ h2, const float* __restrict__ agg,
                         const float* __restrict__ W2, const float* __restrict__ b2,
                         const float* __restrict__ st, const float* __restrict__ age,
                         const int* __restrict__ order, float* __restrict__ flat) {
    int bk = blockIdx.x;
    int b = bk / KPOOL, k = bk % KPOOL;
    int n = order[bk];
    int g = b >> 2, bi = b & 3;
    size_t node = (size_t)g * NN + n;
    int f = threadIdx.x;
    float val = 0.f;
    if (f < DIN) {
        val = xt[(node * GB + bi) * DIN + f];
    } else if (f < DIN + CH) {
        int c = f - DIN;
        val = fmaxf(fmaf(h1[(node * GB + bi) * CH + c], st[c], st[64 + c]), 0.f);
    } else if (f < DIN + 2 * CH) {
        int c = f - DIN - CH;
        val = fmaxf(fmaf(h2[(node * GB + bi) * CH + c], st[128 + c], st[192 + c]), 0.f);
    } else if (f < FTOT) {
        int c = f - DIN - 2 * CH;
        const float* __restrict__ Ar = agg + (node * GB + bi) * CH;
        float s = b2[c];
#pragma unroll 8
        for (int kk = 0; kk < 64; ++kk)
            s = fmaf(Ar[kk], W2[kk * 64 + c], s);   // Ar broadcast, W2 coalesced
        val = fmaxf(s, 0.f);
    }
    if (f < FTOT) flat[(size_t)b * FLATW + k * FTOT + f] = val;
    if (bk == 0 && f >= FTOT && f < FTOT + NB)
        flat[(size_t)(f - FTOT) * FLATW + (FLATW - 1)] = age[f - FTOT];
}

// ---------------- MLP head layer 1: hm += flat @ mW0 (k-split, atomics) ----------------
__global__ void k_head1(const float* __restrict__ flat, const float* __restrict__ mW0,
                        float* hm) {
    int tid = threadIdx.x;
    int j4 = (tid & 31) * 4;       // 32 groups * 4 = 128 cols
    int b0 = (tid >> 5) * 4;       // 8 groups * 4 = 32 rows
    int kbase = blockIdx.x * 64;
    float acc[4][4];
#pragma unroll
    for (int i = 0; i < 4; i++)
#pragma unroll
        for (int jj = 0; jj < 4; jj++) acc[i][jj] = 0.f;
    int kend = FLATW - kbase; if (kend > 64) kend = 64;
    for (int kk = 0; kk < kend; ++kk) {
        int k = kbase + kk;
        float4 w = *(const float4*)(mW0 + (size_t)k * NH + j4);
#pragma unroll
        for (int i = 0; i < 4; i++) {
            float fv = flat[(size_t)(b0 + i) * FLATW + k];
            acc[i][0] = fmaf(fv, w.x, acc[i][0]);
            acc[i][1] = fmaf(fv, w.y, acc[i][1]);
            acc[i][2] = fmaf(fv, w.z, acc[i][2]);
            acc[i][3] = fmaf(fv, w.w, acc[i][3]);
        }
    }
#pragma unroll
    for (int i = 0; i < 4; i++)
#pragma unroll
        for (int jj = 0; jj < 4; jj++)
            atomicAdd(&hm[(size_t)(b0 + i) * NH + j4 + jj], acc[i][jj]);
}

// ---------------- head layer 2 + log_softmax ----------------
__global__ void k_head2(const float* __restrict__ hm, const float* __restrict__ mb0,
                        const float* __restrict__ mW1, const float* __restrict__ mb1,
                        float* __restrict__ out) {
    __shared__ float vals[64];
    int tid = threadIdx.x;  // 64 = 32 b * 2 o
    int b = tid >> 1, o = tid & 1;
    float acc = mb1[o];
    for (int j = 0; j < NH; ++j) {
        float hv = fmaxf(hm[b * NH + j] + mb0[j], 0.f);
        acc = fmaf(hv, mW1[j * 2 + o], acc);
    }
    vals[tid] = acc;
    __syncthreads();
    float v0 = vals[b * 2], v1 = vals[b * 2 + 1];
    float m = fmaxf(v0, v1);
    float lse = m + logf(expf(v0 - m) + expf(v1 - m));
    out[tid] = acc - lse;
}

extern "C" void kernel_launch(void* const* d_in, const int* in_sizes, int n_in,
                              void* d_out, int out_size, void* d_ws, size_t ws_size,
                              hipStream_t stream) {
    const float* x    = (const float*)d_in[0];
    const float* age  = (const float*)d_in[1];
    const float* attr = (const float*)d_in[2];
    const float* W0   = (const float*)d_in[3];
    const float* b0   = (const float*)d_in[4];
    const float* W1   = (const float*)d_in[5];
    const float* b1   = (const float*)d_in[6];
    const float* W2   = (const float*)d_in[7];
    const float* b2   = (const float*)d_in[8];
    const float* g0   = (const float*)d_in[9];
    const float* be0  = (const float*)d_in[10];
    const float* g1   = (const float*)d_in[11];
    const float* be1  = (const float*)d_in[12];
    const float* mW0  = (const float*)d_in[13];
    const float* mb0  = (const float*)d_in[14];
    const float* mW1  = (const float*)d_in[15];
    const float* mb1  = (const float*)d_in[16];
    const int* erow   = (const int*)d_in[17];
    const int* ecol   = (const int*)d_in[18];
    float* out = (float*)d_out;

    // workspace layout (floats); all float4-aligned
    float* ws     = (float*)d_ws;
    float* deg    = ws;                                  // 5008
    float* dinv   = deg + 5008;                          // 5008
    int*   counts = (int*)(dinv + 5008);                 // 5008
    int*   rowptr = counts + 5008;                       // 5008
    int*   cursor = rowptr + 5008;                       // 5008
    int*   csr_col= cursor + 5008;                       // NEPAD
    float* csr_nv = (float*)(csr_col + NEPAD);           // NEPAD
    float* stats  = csr_nv + NEPAD;                      // 2*32*128 = 8192
    float* st     = stats + 2 * NSLOT * 128;             // 256 (s0,t0,s1,t1)
    float* sc     = st + 256;                            // NB*NN = 160000 (scores)
    int*   order  = (int*)(sc + NB * NN);                // 960
    float* flat   = (float*)(order + 960);               // 32*6241
    float* hm     = flat + (size_t)NB * FLATW;           // 4096
    float* xt     = hm + 4096;                           // (G8,N,4,16)
    float* h1     = xt + (size_t)NB * NN * DIN;          // (G8,N,4,64) each
    float* h2     = h1 + (size_t)NB * NN * CH;
    float* agg    = h2 + (size_t)NB * NN * CH;           // layer-2 aggregate (pre-GEMM)

    // graph build
    k_init<<<32, 256, 0, stream>>>(deg, counts, stats, hm);
    k_edgetr<<<NEB + (NB * NN + 255) / 256, 256, 0, stream>>>(attr, erow, deg, counts, x, xt);
    k_scan<<<1, 1024, 0, stream>>>(counts, deg, rowptr, cursor, dinv);
    k_build<<<(NE + NN + 255) / 256, 256, 0, stream>>>(erow, ecol, attr, dinv, counts, rowptr, cursor, csr_col, csr_nv);

    const int NBLK = ((NN + NPB - 1) / NPB) * NG;   // 313 * 8
    // fused layers (gather + per-wave GEMM + slot-spread BN stats + inline BN-in)
    k_layer<16, 0, 1, 0><<<NBLK, 256, 0, stream>>>(xt, nullptr, nullptr, nullptr, W0, b0, rowptr, csr_col, csr_nv, dinv, h1, stats, nullptr);
    k_layer<64, 1, 1, 0><<<NBLK, 256, 0, stream>>>(h1, stats, g0, be0, W1, b1, rowptr, csr_col, csr_nv, dinv, h2, stats + NSLOT * 128, nullptr);
    k_layer<64, 1, 0, 1><<<NBLK, 256, 0, stream>>>(h2, stats + NSLOT * 128, g1, be1, W2, b2, rowptr, csr_col, csr_nv, dinv, agg, nullptr, sc);

    // bn scale/shift for gather + sort-pool + gather (deferred GEMM) + head
    k_bnfin<<<1, 128, 0, stream>>>(stats, g0, be0, g1, be1, st);
    k_toppool<<<NB, 1024, 0, stream>>>(sc, order);
    k_gather<<<NB * KPOOL, 256, 0, stream>>>(xt, h1, h2, agg, W2, b2, st, age, order, flat);
    k_head1<<<(FLATW + 63) / 64, 256, 0, stream>>>(flat, mW0, hm);
    k_head2<<<1, 64, 0, stream>>>(hm, mb0, mW1, mb1, out);
}

// Round 18
// 364.832 us; speedup vs baseline: 1.2887x; 1.0029x over previous
//
#include <hip/hip_runtime.h>
#include <math.h>

// Problem constants (from reference setup_inputs)
#define NN    5000      // nodes
#define NE    80000     // edges
#define NB    32        // batch
#define DIN   16        // input feat
#define CH    64        // conv channels
#define KPOOL 30
#define FTOT  208      // 16 + 3*64
#define FLATW 6241     // KPOOL*FTOT + 1
#define NH    128      // MLP hidden
#define NG    8        // batch groups (one per XCD; G>8 useless: 2 groups share an XCD — R14)
#define GB    4        // batches per group
#define NPB   16       // nodes per block (4 per wave)
#define NPAD  5008     // perm array size (grid covers 313*16)
#define NEPAD (NE + 4 * NN)   // CSR rows padded to multiple of 4
#define NSLOT 32       // stats atomic-spread slots (contention 2504 -> ~78)

// Feature tensors use BATCH-SPLIT NODE-MAJOR layout: (G=8, N, 4, C).
// Nodes processed in DEGREE-SORTED order (perm) for wave/block load balance.

// ---------------- setup kernels ----------------

__global__ void k_init(float* deg, int* counts, float* stats, float* hm, int* perm) {
    int i = blockIdx.x * 256 + threadIdx.x;
    if (i < NN) { deg[i] = 1.0f; counts[i] = 0; }   // deg starts at self-loop value 1
    if (i < 2 * NSLOT * 128) stats[i] = 0.0f;       // [2 layers][32 slots][128]
    if (i < 4096) hm[i] = 0.0f;
    if (i >= NN && i < NPAD) perm[i] = NN;          // tail -> invalid marker
}

// merged: edge-degree atomics (blocks 0..312) + x transpose (blocks 313..937)
#define NEB 313
__global__ void k_edgetr(const float* __restrict__ attr, const int* __restrict__ erow,
                         float* deg, int* counts,
                         const float* __restrict__ x, float* __restrict__ xt) {
    if (blockIdx.x < NEB) {
        int e = blockIdx.x * 256 + threadIdx.x;
        if (e < NE) {
            int r = erow[e];
            atomicAdd(&deg[r], attr[e]);
            atomicAdd(&counts[r], 1);
        }
    } else {
        int idx = (blockIdx.x - NEB) * 256 + threadIdx.x;
        if (idx >= NB * NN) return;
        int b = idx / NN, n = idx % NN;
        int g = b >> 2, bi = b & 3;
        const float4* src = (const float4*)(x + (size_t)idx * DIN);
        float4* dst = (float4*)(xt + (((size_t)g * NN + n) * GB + bi) * DIN);
        dst[0] = src[0]; dst[1] = src[1]; dst[2] = src[2]; dst[3] = src[3];
    }
}

// scan PADDED counts + dinv + DEGREE-SORT permutation (counting sort, 256 buckets)
__global__ __launch_bounds__(1024) void k_scan(const int* __restrict__ counts,
                                               const float* __restrict__ deg,
                                               int* rowptr, int* cursor, float* dinv,
                                               int* perm) {
    __shared__ int wsum[16], woff[16];
    __shared__ int carry_sh;
    __shared__ int hist[256];
    int t = threadIdx.x;
    int lane = t & 63, wid = t >> 6;
    if (t == 0) carry_sh = 0;
    if (t < 256) hist[t] = 0;
    __syncthreads();
    for (int base = 0; base < NN; base += 1024) {
        int carry = carry_sh;
        int i = base + t;
        int v = 0;
        if (i < NN) {
            v = (counts[i] + 3) & ~3;
            dinv[i] = 1.0f / sqrtf(deg[i]);   // deg >= 1 always
            atomicAdd(&hist[min(v >> 2, 255)], 1);
        }
        int s = v;
#pragma unroll
        for (int off = 1; off < 64; off <<= 1) {
            int o = __shfl_up(s, off);
            if (lane >= off) s += o;
        }
        if (lane == 63) wsum[wid] = s;
        __syncthreads();
        if (t < 16) {
            int w = wsum[t];
#pragma unroll
            for (int off = 1; off < 16; off <<= 1) {
                int o = __shfl_up(w, off);
                if (t >= off) w += o;
            }
            woff[t] = w;
        }
        __syncthreads();
        int inc = s + (wid > 0 ? woff[wid - 1] : 0) + carry;
        if (i < NN) {
            rowptr[i + 1] = inc;
            cursor[i] = inc - v;
        }
        if (t == 1023) carry_sh = carry + woff[15];
        __syncthreads();
    }
    if (t == 0) rowptr[0] = 0;
    // ---- counting-sort by bucket: exclusive prefix over hist, then scatter ----
    int mycnt = (t < 256) ? hist[t] : 0;
    for (int off = 1; off < 256; off <<= 1) {
        int v = (t < 256 && t >= off) ? hist[t - off] : 0;
        __syncthreads();
        if (t < 256) hist[t] += v;
        __syncthreads();
    }
    if (t < 256) hist[t] -= mycnt;    // exclusive offsets (reused as cursors)
    __syncthreads();
    for (int i = t; i < NN; i += 1024) {
        int b = min(((counts[i] + 3) & ~3) >> 2, 255);
        int pos = atomicAdd(&hist[b], 1);
        perm[pos] = i;
    }
}

// merged: CSR scatter (t < NE) + zero-weight pad fill (t-NE < NN); disjoint slots
__global__ void k_build(const int* __restrict__ erow, const int* __restrict__ ecol,
                        const float* __restrict__ attr, const float* __restrict__ dinv,
                        const int* __restrict__ counts, const int* __restrict__ rowptr,
                        int* cursor, int* csr_col, float* csr_nv) {
    int t = blockIdx.x * 256 + threadIdx.x;
    if (t < NE) {
        int r = erow[t], c = ecol[t];
        int pos = atomicAdd(&cursor[r], 1);
        csr_col[pos] = c;
        csr_nv[pos] = dinv[r] * attr[t] * dinv[c];
    } else if (t - NE < NN) {
        int i = t - NE;
        int cnt = counts[i];
        int pcnt = (cnt + 3) & ~3;
        int base = rowptr[i + 1] - pcnt;
        for (int p = base + cnt; p < base + pcnt; ++p) { csr_col[p] = i; csr_nv[p] = 0.0f; }
    }
}

// ---------------- helpers ----------------
template<int ACT>
__device__ __forceinline__ float4 actv(float4 v, float4 s, float4 t) {
    if (ACT) {
        v.x = fmaxf(fmaf(v.x, s.x, t.x), 0.f);
        v.y = fmaxf(fmaf(v.y, s.y, t.y), 0.f);
        v.z = fmaxf(fmaf(v.z, s.z, t.z), 0.f);
        v.w = fmaxf(fmaf(v.w, s.w, t.w), 0.f);
    }
    return v;
}
__device__ __forceinline__ void fma4(float4& a, float w, float4 v) {
    a.x = fmaf(w, v.x, a.x); a.y = fmaf(w, v.y, a.y);
    a.z = fmaf(w, v.z, a.z); a.w = fmaf(w, v.w, a.w);
}

// ---------------- fused GCN layer ----------------
// Block = (16 degree-sorted nodes via perm, group g). Stage 1 (CIN=64): 2
// interleaved node pairs per wave (8 gathers in flight); sorted degrees make
// pair trip-counts equal (no clamp waste). Tail bundles: col sanitized to 0 +
// weight 0 (R16 crash: CSR tail is 0xAA-poisoned; zero-weight loads still
// need valid addresses). NO stage1->stage2 barrier: stage 2 reads only the
// wave's private Aw slice — waves fully decoupled (R17 occupancy fix).
// Stage 2 (SCORE=0): R9 per-wave GEMM (W float4 global + scalar LDS A; do NOT
// vectorize A reads — R10). SCORE=1: write agg + compact score; GEMM deferred
// to k_gather. STATS: slot-spread atomics (its barriers protect As reuse).
template<int CIN, int ACT, int STATS, int SCORE>
__global__ __launch_bounds__(256) void k_layer(
        const float* __restrict__ in, const float* __restrict__ bnstats,
        const float* __restrict__ gamma, const float* __restrict__ beta,
        const float* __restrict__ W, const float* __restrict__ bias,
        const int* __restrict__ rowptr, const int* __restrict__ csr_col,
        const float* __restrict__ csr_nv, const float* __restrict__ dinv,
        const int* __restrict__ perm,
        float* __restrict__ out, float* __restrict__ stats,
        float* __restrict__ score) {
    constexpr int ALS = (CIN == 64) ? 68 : 20;
    __shared__ float As[4 * 16 * ALS];
    __shared__ float stl[ACT ? 128 : 4];
    int tid = threadIdx.x;
    int wid = tid >> 6, lane = tid & 63;
    int g = blockIdx.x & 7;                      // XCD round-robin
    int nb = (blockIdx.x >> 3) * NPB;
    int base = nb + wid * 4;
    float* Aw = As + wid * 16 * ALS;
    const int4 pid = *(const int4*)(perm + base);   // 4 node ids (degree-sorted)

    if (ACT) {
        if (tid < 64) {
            float su = 0.f, qu = 0.f;
#pragma unroll
            for (int s = 0; s < NSLOT; ++s) {
                su += bnstats[s * 128 + tid];
                qu += bnstats[s * 128 + 64 + tid];
            }
            const float inv = 1.0f / (float)(NB * NN);
            float mu = su * inv;
            float var = qu * inv - mu * mu;
            float sc = gamma[tid] / sqrtf(var + 1e-5f);
            stl[tid] = sc;
            stl[64 + tid] = fmaf(-mu, sc, beta[tid]);
        }
        __syncthreads();
    }

    if (CIN == 64) {
        const float4* __restrict__ in4 = (const float4*)in + (size_t)g * NN * 64;
        int c4 = lane & 15, bi = lane >> 4;
        float4 sv = {1.f,1.f,1.f,1.f}, tv = {0.f,0.f,0.f,0.f};
        if (ACT) { sv = ((const float4*)stl)[c4]; tv = ((const float4*)(stl + 64))[c4]; }
#pragma unroll
        for (int pr = 0; pr < 2; ++pr) {
            int id0 = (pr == 0) ? pid.x : pid.z;
            int id1 = (pr == 0) ? pid.y : pid.w;
            bool vn0 = id0 < NN, vn1 = id1 < NN;
            int rc0 = vn0 ? id0 : 0, rc1 = vn1 ? id1 : 0;
            float dd0 = dinv[rc0]; dd0 *= dd0;
            float dd1 = dinv[rc1]; dd1 *= dd1;
            float4 a0 = {0.f,0.f,0.f,0.f}, a1 = {0.f,0.f,0.f,0.f};
            {
                float4 v0 = actv<ACT>(in4[(size_t)rc0 * 64 + lane], sv, tv);
                float4 v1 = actv<ACT>(in4[(size_t)rc1 * 64 + lane], sv, tv);
                if (vn0) { a0.x = dd0 * v0.x; a0.y = dd0 * v0.y; a0.z = dd0 * v0.z; a0.w = dd0 * v0.w; }
                if (vn1) { a1.x = dd1 * v1.x; a1.y = dd1 * v1.y; a1.z = dd1 * v1.z; a1.w = dd1 * v1.w; }
            }
            int p0a = rowptr[rc0], na = vn0 ? (rowptr[rc0 + 1] - p0a) >> 2 : 0;
            int p0b = rowptr[rc1], nbv = vn1 ? (rowptr[rc1 + 1] - p0b) >> 2 : 0;
            int mx = max(na, nbv);
            for (int bb = 0; bb < mx; ++bb) {
                int ea = min(p0a + 4 * bb, NEPAD - 4);
                int eb = min(p0b + 4 * bb, NEPAD - 4);
                bool va = bb < na, vb = bb < nbv;
                int4   ca = *(const int4*)(csr_col + ea);
                float4 wa = *(const float4*)(csr_nv + ea);
                int4   cb = *(const int4*)(csr_col + eb);
                float4 wb = *(const float4*)(csr_nv + eb);
                if (!va) { wa.x = 0.f; wa.y = 0.f; wa.z = 0.f; wa.w = 0.f;
                           ca.x = 0; ca.y = 0; ca.z = 0; ca.w = 0; }   // poisoned tail
                if (!vb) { wb.x = 0.f; wb.y = 0.f; wb.z = 0.f; wb.w = 0.f;
                           cb.x = 0; cb.y = 0; cb.z = 0; cb.w = 0; }
                float4 u0 = in4[(size_t)ca.x * 64 + lane];
                float4 u1 = in4[(size_t)ca.y * 64 + lane];
                float4 u2 = in4[(size_t)ca.z * 64 + lane];
                float4 u3 = in4[(size_t)ca.w * 64 + lane];
                float4 t0 = in4[(size_t)cb.x * 64 + lane];
                float4 t1 = in4[(size_t)cb.y * 64 + lane];
                float4 t2 = in4[(size_t)cb.z * 64 + lane];
                float4 t3 = in4[(size_t)cb.w * 64 + lane];
                fma4(a0, wa.x, actv<ACT>(u0, sv, tv));
                fma4(a0, wa.y, actv<ACT>(u1, sv, tv));
                fma4(a0, wa.z, actv<ACT>(u2, sv, tv));
                fma4(a0, wa.w, actv<ACT>(u3, sv, tv));
                fma4(a1, wb.x, actv<ACT>(t0, sv, tv));
                fma4(a1, wb.y, actv<ACT>(t1, sv, tv));
                fma4(a1, wb.z, actv<ACT>(t2, sv, tv));
                fma4(a1, wb.w, actv<ACT>(t3, sv, tv));
            }
            *(float4*)(Aw + ((pr * 2 + 0) * 4 + bi) * ALS + c4 * 4) = a0;
            *(float4*)(Aw + ((pr * 2 + 1) * 4 + bi) * ALS + c4 * 4) = a1;
        }
    } else {
        const float* __restrict__ inr = in + (size_t)g * NN * 64;   // row = 64 floats
        int ids[4] = {pid.x, pid.y, pid.z, pid.w};
#pragma unroll
        for (int i = 0; i < 4; ++i) {
            int r = ids[i];
            float a = 0.f;
            if (r < NN) {
                float d = dinv[r];
                a = d * d * inr[(size_t)r * 64 + lane];
                int p0 = rowptr[r], p1 = rowptr[r + 1];
                for (int e = p0; e < p1; e += 4) {
                    int4   cc = *(const int4*)(csr_col + e);
                    float4 ww = *(const float4*)(csr_nv + e);
                    float v0 = inr[(size_t)cc.x * 64 + lane];
                    float v1 = inr[(size_t)cc.y * 64 + lane];
                    float v2 = inr[(size_t)cc.z * 64 + lane];
                    float v3 = inr[(size_t)cc.w * 64 + lane];
                    a = fmaf(ww.x, v0, a);
                    a = fmaf(ww.y, v1, a);
                    a = fmaf(ww.z, v2, a);
                    a = fmaf(ww.w, v3, a);
                }
            }
            Aw[(i * 4 + (lane >> 4)) * ALS + (lane & 15)] = a;
        }
    }
    // NO __syncthreads here: stage 2 reads only this wave's Aw slice.

    int colq = lane & 15, rowq = lane >> 4;
    int node = (rowq == 0) ? pid.x : (rowq == 1) ? pid.y : (rowq == 2) ? pid.z : pid.w;

    if (!SCORE) {
        // ---- stage 2: per-wave GEMM; thread -> (node rowq, colq) [R9 shape] ----
        const float4* __restrict__ W4 = (const float4*)W;
        float4 bb = ((const float4*)bias)[colq];
        float4 o[4];
#pragma unroll
        for (int i = 0; i < 4; ++i) o[i] = bb;
#pragma unroll 8
        for (int k = 0; k < CIN; ++k) {
            float4 w4 = W4[k * 16 + colq];
#pragma unroll
            for (int i = 0; i < 4; ++i) {
                float a = Aw[(rowq * 4 + i) * ALS + k];
                fma4(o[i], a, w4);
            }
        }
        if (node < NN) {
            float4* __restrict__ op = (float4*)(out + ((size_t)g * NN + node) * 256);
#pragma unroll
            for (int i = 0; i < 4; ++i) op[i * 16 + colq] = o[i];
        }

        if (STATS) {
            float4 s4 = {0,0,0,0}, q4 = {0,0,0,0};
            if (node < NN) {
#pragma unroll
                for (int i = 0; i < 4; ++i) {
                    s4.x += o[i].x; s4.y += o[i].y; s4.z += o[i].z; s4.w += o[i].w;
                    q4.x = fmaf(o[i].x, o[i].x, q4.x); q4.y = fmaf(o[i].y, o[i].y, q4.y);
                    q4.z = fmaf(o[i].z, o[i].z, q4.z); q4.w = fmaf(o[i].w, o[i].w, q4.w);
                }
            }
            s4.x += __shfl_xor(s4.x, 16); s4.y += __shfl_xor(s4.y, 16);
            s4.z += __shfl_xor(s4.z, 16); s4.w += __shfl_xor(s4.w, 16);
            q4.x += __shfl_xor(q4.x, 16); q4.y += __shfl_xor(q4.y, 16);
            q4.z += __shfl_xor(q4.z, 16); q4.w += __shfl_xor(q4.w, 16);
            s4.x += __shfl_xor(s4.x, 32); s4.y += __shfl_xor(s4.y, 32);
            s4.z += __shfl_xor(s4.z, 32); s4.w += __shfl_xor(s4.w, 32);
            q4.x += __shfl_xor(q4.x, 32); q4.y += __shfl_xor(q4.y, 32);
            q4.z += __shfl_xor(q4.z, 32); q4.w += __shfl_xor(q4.w, 32);
            __syncthreads();   // all waves done with As -> reuse as scratch
            if (lane < 16) {
                float* S = As + wid * 128;
                *(float4*)(S + lane * 8) = s4;
                *(float4*)(S + lane * 8 + 4) = q4;
            }
            __syncthreads();
            if (tid < 64) {
                int cq = tid >> 2, comp = tid & 3;
                float s = 0.f, q = 0.f;
#pragma unroll
                for (int w = 0; w < 4; ++w) {
                    s += As[w * 128 + cq * 8 + comp];
                    q += As[w * 128 + cq * 8 + 4 + comp];
                }
                float* sl = stats + (blockIdx.x & (NSLOT - 1)) * 128;
                atomicAdd(&sl[tid], s);
                atomicAdd(&sl[64 + tid], q);
            }
        }
    } else {
        // ---- SCORE mode: write agg from LDS + compact relu'd score (ch 63) ----
        if (node < NN) {
            float4* __restrict__ op = (float4*)(out + ((size_t)g * NN + node) * 256);
#pragma unroll
            for (int i = 0; i < 4; ++i)
                op[i * 16 + colq] = *(const float4*)(Aw + (rowq * 4 + i) * ALS + colq * 4);
        }
        if (lane < 16) {
            int q = lane >> 2;
            int nd = (q == 0) ? pid.x : (q == 1) ? pid.y : (q == 2) ? pid.z : pid.w;
            if (nd < NN) {
                float s = bias[63];
                const float* Ar = Aw + lane * ALS;   // row lane = (node lane>>2, bi lane&3)
#pragma unroll 8
                for (int k = 0; k < 64; ++k)
                    s = fmaf(Ar[k], W[k * 64 + 63], s);
                score[((size_t)g * NN + nd) * 4 + (lane & 3)] = fmaxf(s, 0.f);
            }
        }
    }
}

// compute BOTH layers' scale/shift for k_gather (layers compute their own inline)
__global__ void k_bnfin(const float* __restrict__ stats,
                        const float* __restrict__ g0, const float* __restrict__ be0,
                        const float* __restrict__ g1, const float* __restrict__ be1,
                        float* st) {
    int tid = threadIdx.x;  // 128
    int c = tid & 63, layer = tid >> 6;
    const float* sb = stats + layer * NSLOT * 128;
    float su = 0.f, qu = 0.f;
#pragma unroll
    for (int s = 0; s < NSLOT; ++s) {
        su += sb[s * 128 + c];
        qu += sb[s * 128 + 64 + c];
    }
    const float inv = 1.0f / (float)(NB * NN);
    float mu = su * inv;
    float var = qu * inv - mu * mu;
    float g = layer ? g1[c] : g0[c];
    float be = layer ? be1[c] : be0[c];
    float sc = g / sqrtf(var + 1e-5f);
    st[layer * 128 + c] = sc;
    st[layer * 128 + 64 + c] = fmaf(-mu, sc, be);
}

// ---------------- global_sort_pool: register top-30 on compact score array ----
__global__ __launch_bounds__(1024) void k_toppool(const float* __restrict__ sc, int* order) {
    __shared__ unsigned long long wbest[16];
    __shared__ unsigned long long winner;
    int b = blockIdx.x, tid = threadIdx.x;
    int g = b >> 2, bi = b & 3;
    int lane = tid & 63, wid = tid >> 6;
    unsigned long long key[5];
#pragma unroll
    for (int j = 0; j < 5; ++j) {
        int n = tid + j * 1024;
        unsigned long long k = 0;
        if (n < NN) {
            float v = sc[((size_t)g * NN + n) * GB + bi];   // already relu'd
            k = ((unsigned long long)__float_as_uint(v) << 32) | (unsigned int)(NN - n);
        }
        key[j] = k;
    }
    for (int k = 0; k < KPOOL; ++k) {
        unsigned long long best = key[0];
#pragma unroll
        for (int j = 1; j < 5; ++j) best = (key[j] > best) ? key[j] : best;
#pragma unroll
        for (int off = 1; off < 64; off <<= 1) {
            unsigned long long o = __shfl_xor(best, off);
            best = (o > best) ? o : best;
        }
        if (lane == 0) wbest[wid] = best;
        __syncthreads();
        if (tid == 0) {
            unsigned long long w = wbest[0];
#pragma unroll
            for (int i = 1; i < 16; ++i) w = (wbest[i] > w) ? wbest[i] : w;
            winner = w;
            order[b * KPOOL + k] = NN - (int)(w & 0xFFFFFFFFu);
        }
        __syncthreads();
        int n = NN - (int)(winner & 0xFFFFFFFFu);
        if ((n & 1023) == tid) key[n >> 10] = 0;   // remove winner (owner thread)
    }
}

// ---------------- gather selected nodes into flat (B, 6241) ----------------
// h3 branch does the DEFERRED layer-2 GEMM (64 wide) from agg — only 960
// (b,node) pairs ever need it.
__global__ void k_gather(const float* __restrict__ xt, const float* __restrict__ h1,
                         const float* __restrict__ h2, const float* __restrict__ agg,
                         const float* __restrict__ W2, const float* __restrict__ b2,
                         const float* __restrict__ st, const float* __restrict__ age,
                         const int* __restrict__ order, float* __restrict__ flat) {
    int bk = blockIdx.x;
    int b = bk / KPOOL, k = bk % KPOOL;
    int n = order[bk];
    int g = b >> 2, bi = b & 3;
    size_t node = (size_t)g * NN + n;
    int f = threadIdx.x;
    float val = 0.f;
    if (f < DIN) {
        val = xt[(node * GB + bi) * DIN + f];
    } else if (f < DIN + CH) {
        int c = f - DIN;
        val = fmaxf(fmaf(h1[(node * GB + bi) * CH + c], st[c], st[64 + c]), 0.f);
    } else if (f < DIN + 2 * CH) {
        int c = f - DIN - CH;
        val = fmaxf(fmaf(h2[(node * GB + bi) * CH + c], st[128 + c], st[192 + c]), 0.f);
    } else if (f < FTOT) {
        int c = f - DIN - 2 * CH;
        const float* __restrict__ Ar = agg + (node * GB + bi) * CH;
        float s = b2[c];
#pragma unroll 8
        for (int kk = 0; kk < 64; ++kk)
            s = fmaf(Ar[kk], W2[kk * 64 + c], s);   // Ar broadcast, W2 coalesced
        val = fmaxf(s, 0.f);
    }
    if (f < FTOT) flat[(size_t)b * FLATW + k * FTOT + f] = val;
    if (bk == 0 && f >= FTOT && f < FTOT + NB)
        flat[(size_t)(f - FTOT) * FLATW + (FLATW - 1)] = age[f - FTOT];
}

// ---------------- MLP head layer 1: hm += flat @ mW0 (k-split, atomics) ----------------
__global__ void k_head1(const float* __restrict__ flat, const float* __restrict__ mW0,
                        float* hm) {
    int tid = threadIdx.x;
    int j4 = (tid & 31) * 4;       // 32 groups * 4 = 128 cols
    int b0 = (tid >> 5) * 4;       // 8 groups * 4 = 32 rows
    int kbase = blockIdx.x * 64;
    float acc[4][4];
#pragma unroll
    for (int i = 0; i < 4; i++)
#pragma unroll
        for (int jj = 0; jj < 4; jj++) acc[i][jj] = 0.f;
    int kend = FLATW - kbase; if (kend > 64) kend = 64;
    for (int kk = 0; kk < kend; ++kk) {
        int k = kbase + kk;
        float4 w = *(const float4*)(mW0 + (size_t)k * NH + j4);
#pragma unroll
        for (int i = 0; i < 4; i++) {
            float fv = flat[(size_t)(b0 + i) * FLATW + k];
            acc[i][0] = fmaf(fv, w.x, acc[i][0]);
            acc[i][1] = fmaf(fv, w.y, acc[i][1]);
            acc[i][2] = fmaf(fv, w.z, acc[i][2]);
            acc[i][3] = fmaf(fv, w.w, acc[i][3]);
        }
    }
#pragma unroll
    for (int i = 0; i < 4; i++)
#pragma unroll
        for (int jj = 0; jj < 4; jj++)
            atomicAdd(&hm[(size_t)(b0 + i) * NH + j4 + jj], acc[i][jj]);
}

// ---------------- head layer 2 + log_softmax ----------------
__global__ void k_head2(const float* __restrict__ hm, const float* __restrict__ mb0,
                        const float* __restrict__ mW1, const float* __restrict__ mb1,
                        float* __restrict__ out) {
    __shared__ float vals[64];
    int tid = threadIdx.x;  // 64 = 32 b * 2 o
    int b = tid >> 1, o = tid & 1;
    float acc = mb1[o];
    for (int j = 0; j < NH; ++j) {
        float hv = fmaxf(hm[b * NH + j] + mb0[j], 0.f);
        acc = fmaf(hv, mW1[j * 2 + o], acc);
    }
    vals[tid] = acc;
    __syncthreads();
    float v0 = vals[b * 2], v1 = vals[b * 2 + 1];
    float m = fmaxf(v0, v1);
    float lse = m + logf(expf(v0 - m) + expf(v1 - m));
    out[tid] = acc - lse;
}

extern "C" void kernel_launch(void* const* d_in, const int* in_sizes, int n_in,
                              void* d_out, int out_size, void* d_ws, size_t ws_size,
                              hipStream_t stream) {
    const float* x    = (const float*)d_in[0];
    const float* age  = (const float*)d_in[1];
    const float* attr = (const float*)d_in[2];
    const float* W0   = (const float*)d_in[3];
    const float* b0   = (const float*)d_in[4];
    const float* W1   = (const float*)d_in[5];
    const float* b1   = (const float*)d_in[6];
    const float* W2   = (const float*)d_in[7];
    const float* b2   = (const float*)d_in[8];
    const float* g0   = (const float*)d_in[9];
    const float* be0  = (const float*)d_in[10];
    const float* g1   = (const float*)d_in[11];
    const float* be1  = (const float*)d_in[12];
    const float* mW0  = (const float*)d_in[13];
    const float* mb0  = (const float*)d_in[14];
    const float* mW1  = (const float*)d_in[15];
    const float* mb1  = (const float*)d_in[16];
    const int* erow   = (const int*)d_in[17];
    const int* ecol   = (const int*)d_in[18];
    float* out = (float*)d_out;

    // workspace layout (floats); all float4-aligned
    float* ws     = (float*)d_ws;
    float* deg    = ws;                                  // 5008
    float* dinv   = deg + 5008;                          // 5008
    int*   counts = (int*)(dinv + 5008);                 // 5008
    int*   rowptr = counts + 5008;                       // 5008
    int*   cursor = rowptr + 5008;                       // 5008
    int*   perm   = cursor + 5008;                       // 5008
    int*   csr_col= perm + 5008;                         // NEPAD
    float* csr_nv = (float*)(csr_col + NEPAD);           // NEPAD
    float* stats  = csr_nv + NEPAD;                      // 2*32*128 = 8192
    float* st     = stats + 2 * NSLOT * 128;             // 256 (s0,t0,s1,t1)
    float* sc     = st + 256;                            // NB*NN = 160000 (scores)
    int*   order  = (int*)(sc + NB * NN);                // 960
    float* flat   = (float*)(order + 960);               // 32*6241
    float* hm     = flat + (size_t)NB * FLATW;           // 4096
    float* xt     = hm + 4096;                           // (G8,N,4,16)
    float* h1     = xt + (size_t)NB * NN * DIN;          // (G8,N,4,64) each
    float* h2     = h1 + (size_t)NB * NN * CH;
    float* agg    = h2 + (size_t)NB * NN * CH;           // layer-2 aggregate (pre-GEMM)

    // graph build
    k_init<<<32, 256, 0, stream>>>(deg, counts, stats, hm, perm);
    k_edgetr<<<NEB + (NB * NN + 255) / 256, 256, 0, stream>>>(attr, erow, deg, counts, x, xt);
    k_scan<<<1, 1024, 0, stream>>>(counts, deg, rowptr, cursor, dinv, perm);
    k_build<<<(NE + NN + 255) / 256, 256, 0, stream>>>(erow, ecol, attr, dinv, counts, rowptr, cursor, csr_col, csr_nv);

    const int NBLK = ((NN + NPB - 1) / NPB) * NG;   // 313 * 8
    // fused layers (gather + per-wave GEMM + slot-spread BN stats + inline BN-in)
    k_layer<16, 0, 1, 0><<<NBLK, 256, 0, stream>>>(xt, nullptr, nullptr, nullptr, W0, b0, rowptr, csr_col, csr_nv, dinv, perm, h1, stats, nullptr);
    k_layer<64, 1, 1, 0><<<NBLK, 256, 0, stream>>>(h1, stats, g0, be0, W1, b1, rowptr, csr_col, csr_nv, dinv, perm, h2, stats + NSLOT * 128, nullptr);
    k_layer<64, 1, 0, 1><<<NBLK, 256, 0, stream>>>(h2, stats + NSLOT * 128, g1, be1, W2, b2, rowptr, csr_col, csr_nv, dinv, perm, agg, nullptr, sc);

    // bn scale/shift for gather + sort-pool + gather (deferred GEMM) + head
    k_bnfin<<<1, 128, 0, stream>>>(stats, g0, be0, g1, be1, st);
    k_toppool<<<NB, 1024, 0, stream>>>(sc, order);
    k_gather<<<NB * KPOOL, 256, 0, stream>>>(xt, h1, h2, agg, W2, b2, st, age, order, flat);
    k_head1<<<(FLATW + 63) / 64, 256, 0, stream>>>(flat, mW0, hm);
    k_head2<<<1, 64, 0, stream>>>(hm, mb0, mW1, mb1, out);
}

// Round 19
// 352.485 us; speedup vs baseline: 1.3338x; 1.0350x over previous
//
#include <hip/hip_runtime.h>
#include <math.h>

// Problem constants (from reference setup_inputs)
#define NN    5000      // nodes
#define NE    80000     // edges
#define NB    32        // batch
#define DIN   16        // input feat
#define CH    64        // conv channels
#define KPOOL 30
#define FTOT  208      // 16 + 3*64
#define FLATW 6241     // KPOOL*FTOT + 1
#define NH    128      // MLP hidden
#define NG    8        // batch groups (one per XCD; G>8 useless: 2 groups share an XCD — R14)
#define GB    4        // batches per group
#define NPB   16       // nodes per block (4 per wave)
#define NPAD  5008     // perm array size (grid covers 313*16)
#define NEPAD (NE + 4 * NN)   // CSR rows padded to multiple of 4
#define NSLOT 32       // stats atomic-spread slots (contention 2504 -> ~78)

// Feature tensors use BATCH-SPLIT NODE-MAJOR layout: (G=8, N, 4, C).
// Nodes processed in DESCENDING-degree order (perm): uniform waves + LPT
// block scheduling (R18's ascending order left heavy blocks draining alone).

// ---------------- setup kernels ----------------

__global__ void k_init(float* deg, int* counts, float* stats, float* hm, int* perm) {
    int i = blockIdx.x * 256 + threadIdx.x;
    if (i < NN) { deg[i] = 1.0f; counts[i] = 0; }   // deg starts at self-loop value 1
    if (i < 2 * NSLOT * 128) stats[i] = 0.0f;       // [2 layers][32 slots][128]
    if (i < 4096) hm[i] = 0.0f;
    if (i >= NN && i < NPAD) perm[i] = NN;          // tail -> invalid marker
}

// merged: edge-degree atomics (blocks 0..312) + x transpose (blocks 313..937)
#define NEB 313
__global__ void k_edgetr(const float* __restrict__ attr, const int* __restrict__ erow,
                         float* deg, int* counts,
                         const float* __restrict__ x, float* __restrict__ xt) {
    if (blockIdx.x < NEB) {
        int e = blockIdx.x * 256 + threadIdx.x;
        if (e < NE) {
            int r = erow[e];
            atomicAdd(&deg[r], attr[e]);
            atomicAdd(&counts[r], 1);
        }
    } else {
        int idx = (blockIdx.x - NEB) * 256 + threadIdx.x;
        if (idx >= NB * NN) return;
        int b = idx / NN, n = idx % NN;
        int g = b >> 2, bi = b & 3;
        const float4* src = (const float4*)(x + (size_t)idx * DIN);
        float4* dst = (float4*)(xt + (((size_t)g * NN + n) * GB + bi) * DIN);
        dst[0] = src[0]; dst[1] = src[1]; dst[2] = src[2]; dst[3] = src[3];
    }
}

// scan PADDED counts + dinv + DESCENDING degree-sort perm (counting sort)
__global__ __launch_bounds__(1024) void k_scan(const int* __restrict__ counts,
                                               const float* __restrict__ deg,
                                               int* rowptr, int* cursor, float* dinv,
                                               int* perm) {
    __shared__ int wsum[16], woff[16];
    __shared__ int carry_sh;
    __shared__ int hist[256];
    int t = threadIdx.x;
    int lane = t & 63, wid = t >> 6;
    if (t == 0) carry_sh = 0;
    if (t < 256) hist[t] = 0;
    __syncthreads();
    for (int base = 0; base < NN; base += 1024) {
        int carry = carry_sh;
        int i = base + t;
        int v = 0;
        if (i < NN) {
            v = (counts[i] + 3) & ~3;
            dinv[i] = 1.0f / sqrtf(deg[i]);   // deg >= 1 always
            atomicAdd(&hist[255 - min(v >> 2, 255)], 1);   // DESCENDING buckets
        }
        int s = v;
#pragma unroll
        for (int off = 1; off < 64; off <<= 1) {
            int o = __shfl_up(s, off);
            if (lane >= off) s += o;
        }
        if (lane == 63) wsum[wid] = s;
        __syncthreads();
        if (t < 16) {
            int w = wsum[t];
#pragma unroll
            for (int off = 1; off < 16; off <<= 1) {
                int o = __shfl_up(w, off);
                if (t >= off) w += o;
            }
            woff[t] = w;
        }
        __syncthreads();
        int inc = s + (wid > 0 ? woff[wid - 1] : 0) + carry;
        if (i < NN) {
            rowptr[i + 1] = inc;
            cursor[i] = inc - v;
        }
        if (t == 1023) carry_sh = carry + woff[15];
        __syncthreads();
    }
    if (t == 0) rowptr[0] = 0;
    // ---- counting-sort by (descending) bucket: prefix + scatter ----
    int mycnt = (t < 256) ? hist[t] : 0;
    for (int off = 1; off < 256; off <<= 1) {
        int v = (t < 256 && t >= off) ? hist[t - off] : 0;
        __syncthreads();
        if (t < 256) hist[t] += v;
        __syncthreads();
    }
    if (t < 256) hist[t] -= mycnt;    // exclusive offsets (reused as cursors)
    __syncthreads();
    for (int i = t; i < NN; i += 1024) {
        int b = 255 - min(((counts[i] + 3) & ~3) >> 2, 255);
        int pos = atomicAdd(&hist[b], 1);
        perm[pos] = i;
    }
}

// merged: CSR scatter (t < NE) + zero-weight pad fill (t-NE < NN); disjoint slots
__global__ void k_build(const int* __restrict__ erow, const int* __restrict__ ecol,
                        const float* __restrict__ attr, const float* __restrict__ dinv,
                        const int* __restrict__ counts, const int* __restrict__ rowptr,
                        int* cursor, int* csr_col, float* csr_nv) {
    int t = blockIdx.x * 256 + threadIdx.x;
    if (t < NE) {
        int r = erow[t], c = ecol[t];
        int pos = atomicAdd(&cursor[r], 1);
        csr_col[pos] = c;
        csr_nv[pos] = dinv[r] * attr[t] * dinv[c];
    } else if (t - NE < NN) {
        int i = t - NE;
        int cnt = counts[i];
        int pcnt = (cnt + 3) & ~3;
        int base = rowptr[i + 1] - pcnt;
        for (int p = base + cnt; p < base + pcnt; ++p) { csr_col[p] = i; csr_nv[p] = 0.0f; }
    }
}

// ---------------- helpers ----------------
template<int ACT>
__device__ __forceinline__ float4 actv(float4 v, float4 s, float4 t) {
    if (ACT) {
        v.x = fmaxf(fmaf(v.x, s.x, t.x), 0.f);
        v.y = fmaxf(fmaf(v.y, s.y, t.y), 0.f);
        v.z = fmaxf(fmaf(v.z, s.z, t.z), 0.f);
        v.w = fmaxf(fmaf(v.w, s.w, t.w), 0.f);
    }
    return v;
}
__device__ __forceinline__ void fma4(float4& a, float w, float4 v) {
    a.x = fmaf(w, v.x, a.x); a.y = fmaf(w, v.y, a.y);
    a.z = fmaf(w, v.z, a.z); a.w = fmaf(w, v.w, a.w);
}

// ---------------- fused GCN layer ----------------
// Block = (16 degree-sorted nodes via perm, group g). Stage 1 (CIN=64): 2
// interleaved node pairs per wave (8 gathers in flight); sorted degrees make
// pair trip-counts equal. Tail bundles: col sanitized to 0 + weight 0 (R16
// crash: CSR tail is 0xAA-poisoned; zero-weight loads still need valid
// addresses). NO stage1->stage2 barrier (waves decoupled; R17 fix).
// Stage 2 (SCORE=0): R9 per-wave GEMM (W float4 global + scalar LDS A; do NOT
// vectorize A reads — R10). SCORE=1: write agg + compact score; GEMM deferred
// to k_gather. STATS: slot-spread atomics (its barriers protect As reuse).
template<int CIN, int ACT, int STATS, int SCORE>
__global__ __launch_bounds__(256) void k_layer(
        const float* __restrict__ in, const float* __restrict__ bnstats,
        const float* __restrict__ gamma, const float* __restrict__ beta,
        const float* __restrict__ W, const float* __restrict__ bias,
        const int* __restrict__ rowptr, const int* __restrict__ csr_col,
        const float* __restrict__ csr_nv, const float* __restrict__ dinv,
        const int* __restrict__ perm,
        float* __restrict__ out, float* __restrict__ stats,
        float* __restrict__ score) {
    constexpr int ALS = (CIN == 64) ? 68 : 20;
    __shared__ float As[4 * 16 * ALS];
    __shared__ float stl[ACT ? 128 : 4];
    int tid = threadIdx.x;
    int wid = tid >> 6, lane = tid & 63;
    int g = blockIdx.x & 7;                      // XCD round-robin
    int nb = (blockIdx.x >> 3) * NPB;
    int base = nb + wid * 4;
    float* Aw = As + wid * 16 * ALS;
    const int4 pid = *(const int4*)(perm + base);   // 4 node ids (degree-sorted)

    if (ACT) {
        if (tid < 64) {
            float su = 0.f, qu = 0.f;
#pragma unroll
            for (int s = 0; s < NSLOT; ++s) {
                su += bnstats[s * 128 + tid];
                qu += bnstats[s * 128 + 64 + tid];
            }
            const float inv = 1.0f / (float)(NB * NN);
            float mu = su * inv;
            float var = qu * inv - mu * mu;
            float sc = gamma[tid] / sqrtf(var + 1e-5f);
            stl[tid] = sc;
            stl[64 + tid] = fmaf(-mu, sc, beta[tid]);
        }
        __syncthreads();
    }

    if (CIN == 64) {
        const float4* __restrict__ in4 = (const float4*)in + (size_t)g * NN * 64;
        int c4 = lane & 15, bi = lane >> 4;
        float4 sv = {1.f,1.f,1.f,1.f}, tv = {0.f,0.f,0.f,0.f};
        if (ACT) { sv = ((const float4*)stl)[c4]; tv = ((const float4*)(stl + 64))[c4]; }
#pragma unroll
        for (int pr = 0; pr < 2; ++pr) {
            int id0 = (pr == 0) ? pid.x : pid.z;
            int id1 = (pr == 0) ? pid.y : pid.w;
            bool vn0 = id0 < NN, vn1 = id1 < NN;
            int rc0 = vn0 ? id0 : 0, rc1 = vn1 ? id1 : 0;
            float dd0 = dinv[rc0]; dd0 *= dd0;
            float dd1 = dinv[rc1]; dd1 *= dd1;
            float4 a0 = {0.f,0.f,0.f,0.f}, a1 = {0.f,0.f,0.f,0.f};
            {
                float4 v0 = actv<ACT>(in4[(size_t)rc0 * 64 + lane], sv, tv);
                float4 v1 = actv<ACT>(in4[(size_t)rc1 * 64 + lane], sv, tv);
                if (vn0) { a0.x = dd0 * v0.x; a0.y = dd0 * v0.y; a0.z = dd0 * v0.z; a0.w = dd0 * v0.w; }
                if (vn1) { a1.x = dd1 * v1.x; a1.y = dd1 * v1.y; a1.z = dd1 * v1.z; a1.w = dd1 * v1.w; }
            }
            int p0a = rowptr[rc0], na = vn0 ? (rowptr[rc0 + 1] - p0a) >> 2 : 0;
            int p0b = rowptr[rc1], nbv = vn1 ? (rowptr[rc1 + 1] - p0b) >> 2 : 0;
            int mx = max(na, nbv);
            for (int bb = 0; bb < mx; ++bb) {
                int ea = min(p0a + 4 * bb, NEPAD - 4);
                int eb = min(p0b + 4 * bb, NEPAD - 4);
                bool va = bb < na, vb = bb < nbv;
                int4   ca = *(const int4*)(csr_col + ea);
                float4 wa = *(const float4*)(csr_nv + ea);
                int4   cb = *(const int4*)(csr_col + eb);
                float4 wb = *(const float4*)(csr_nv + eb);
                if (!va) { wa.x = 0.f; wa.y = 0.f; wa.z = 0.f; wa.w = 0.f;
                           ca.x = 0; ca.y = 0; ca.z = 0; ca.w = 0; }   // poisoned tail
                if (!vb) { wb.x = 0.f; wb.y = 0.f; wb.z = 0.f; wb.w = 0.f;
                           cb.x = 0; cb.y = 0; cb.z = 0; cb.w = 0; }
                float4 u0 = in4[(size_t)ca.x * 64 + lane];
                float4 u1 = in4[(size_t)ca.y * 64 + lane];
                float4 u2 = in4[(size_t)ca.z * 64 + lane];
                float4 u3 = in4[(size_t)ca.w * 64 + lane];
                float4 t0 = in4[(size_t)cb.x * 64 + lane];
                float4 t1 = in4[(size_t)cb.y * 64 + lane];
                float4 t2 = in4[(size_t)cb.z * 64 + lane];
                float4 t3 = in4[(size_t)cb.w * 64 + lane];
                fma4(a0, wa.x, actv<ACT>(u0, sv, tv));
                fma4(a0, wa.y, actv<ACT>(u1, sv, tv));
                fma4(a0, wa.z, actv<ACT>(u2, sv, tv));
                fma4(a0, wa.w, actv<ACT>(u3, sv, tv));
                fma4(a1, wb.x, actv<ACT>(t0, sv, tv));
                fma4(a1, wb.y, actv<ACT>(t1, sv, tv));
                fma4(a1, wb.z, actv<ACT>(t2, sv, tv));
                fma4(a1, wb.w, actv<ACT>(t3, sv, tv));
            }
            *(float4*)(Aw + ((pr * 2 + 0) * 4 + bi) * ALS + c4 * 4) = a0;
            *(float4*)(Aw + ((pr * 2 + 1) * 4 + bi) * ALS + c4 * 4) = a1;
        }
    } else {
        const float* __restrict__ inr = in + (size_t)g * NN * 64;   // row = 64 floats
        int ids[4] = {pid.x, pid.y, pid.z, pid.w};
#pragma unroll
        for (int i = 0; i < 4; ++i) {
            int r = ids[i];
            float a = 0.f;
            if (r < NN) {
                float d = dinv[r];
                a = d * d * inr[(size_t)r * 64 + lane];
                int p0 = rowptr[r], p1 = rowptr[r + 1];
                for (int e = p0; e < p1; e += 4) {
                    int4   cc = *(const int4*)(csr_col + e);
                    float4 ww = *(const float4*)(csr_nv + e);
                    float v0 = inr[(size_t)cc.x * 64 + lane];
                    float v1 = inr[(size_t)cc.y * 64 + lane];
                    float v2 = inr[(size_t)cc.z * 64 + lane];
                    float v3 = inr[(size_t)cc.w * 64 + lane];
                    a = fmaf(ww.x, v0, a);
                    a = fmaf(ww.y, v1, a);
                    a = fmaf(ww.z, v2, a);
                    a = fmaf(ww.w, v3, a);
                }
            }
            Aw[(i * 4 + (lane >> 4)) * ALS + (lane & 15)] = a;
        }
    }
    // NO __syncthreads here: stage 2 reads only this wave's Aw slice.

    int colq = lane & 15, rowq = lane >> 4;
    int node = (rowq == 0) ? pid.x : (rowq == 1) ? pid.y : (rowq == 2) ? pid.z : pid.w;

    if (!SCORE) {
        // ---- stage 2: per-wave GEMM; thread -> (node rowq, colq) [R9 shape] ----
        const float4* __restrict__ W4 = (const float4*)W;
        float4 bb = ((const float4*)bias)[colq];
        float4 o[4];
#pragma unroll
        for (int i = 0; i < 4; ++i) o[i] = bb;
#pragma unroll 8
        for (int k = 0; k < CIN; ++k) {
            float4 w4 = W4[k * 16 + colq];
#pragma unroll
            for (int i = 0; i < 4; ++i) {
                float a = Aw[(rowq * 4 + i) * ALS + k];
                fma4(o[i], a, w4);
            }
        }
        if (node < NN) {
            float4* __restrict__ op = (float4*)(out + ((size_t)g * NN + node) * 256);
#pragma unroll
            for (int i = 0; i < 4; ++i) op[i * 16 + colq] = o[i];
        }

        if (STATS) {
            float4 s4 = {0,0,0,0}, q4 = {0,0,0,0};
            if (node < NN) {
#pragma unroll
                for (int i = 0; i < 4; ++i) {
                    s4.x += o[i].x; s4.y += o[i].y; s4.z += o[i].z; s4.w += o[i].w;
                    q4.x = fmaf(o[i].x, o[i].x, q4.x); q4.y = fmaf(o[i].y, o[i].y, q4.y);
                    q4.z = fmaf(o[i].z, o[i].z, q4.z); q4.w = fmaf(o[i].w, o[i].w, q4.w);
                }
            }
            s4.x += __shfl_xor(s4.x, 16); s4.y += __shfl_xor(s4.y, 16);
            s4.z += __shfl_xor(s4.z, 16); s4.w += __shfl_xor(s4.w, 16);
            q4.x += __shfl_xor(q4.x, 16); q4.y += __shfl_xor(q4.y, 16);
            q4.z += __shfl_xor(q4.z, 16); q4.w += __shfl_xor(q4.w, 16);
            s4.x += __shfl_xor(s4.x, 32); s4.y += __shfl_xor(s4.y, 32);
            s4.z += __shfl_xor(s4.z, 32); s4.w += __shfl_xor(s4.w, 32);
            q4.x += __shfl_xor(q4.x, 32); q4.y += __shfl_xor(q4.y, 32);
            q4.z += __shfl_xor(q4.z, 32); q4.w += __shfl_xor(q4.w, 32);
            __syncthreads();   // all waves done with As -> reuse as scratch
            if (lane < 16) {
                float* S = As + wid * 128;
                *(float4*)(S + lane * 8) = s4;
                *(float4*)(S + lane * 8 + 4) = q4;
            }
            __syncthreads();
            if (tid < 64) {
                int cq = tid >> 2, comp = tid & 3;
                float s = 0.f, q = 0.f;
#pragma unroll
                for (int w = 0; w < 4; ++w) {
                    s += As[w * 128 + cq * 8 + comp];
                    q += As[w * 128 + cq * 8 + 4 + comp];
                }
                float* sl = stats + (blockIdx.x & (NSLOT - 1)) * 128;
                atomicAdd(&sl[tid], s);
                atomicAdd(&sl[64 + tid], q);
            }
        }
    } else {
        // ---- SCORE mode: write agg from LDS + compact relu'd score (ch 63) ----
        if (node < NN) {
            float4* __restrict__ op = (float4*)(out + ((size_t)g * NN + node) * 256);
#pragma unroll
            for (int i = 0; i < 4; ++i)
                op[i * 16 + colq] = *(const float4*)(Aw + (rowq * 4 + i) * ALS + colq * 4);
        }
        if (lane < 16) {
            int q = lane >> 2;
            int nd = (q == 0) ? pid.x : (q == 1) ? pid.y : (q == 2) ? pid.z : pid.w;
            if (nd < NN) {
                float s = bias[63];
                const float* Ar = Aw + lane * ALS;   // row lane = (node lane>>2, bi lane&3)
#pragma unroll 8
                for (int k = 0; k < 64; ++k)
                    s = fmaf(Ar[k], W[k * 64 + 63], s);
                score[((size_t)g * NN + nd) * 4 + (lane & 3)] = fmaxf(s, 0.f);
            }
        }
    }
}

// compute BOTH layers' scale/shift for k_gather (layers compute their own inline)
__global__ void k_bnfin(const float* __restrict__ stats,
                        const float* __restrict__ g0, const float* __restrict__ be0,
                        const float* __restrict__ g1, const float* __restrict__ be1,
                        float* st) {
    int tid = threadIdx.x;  // 128
    int c = tid & 63, layer = tid >> 6;
    const float* sb = stats + layer * NSLOT * 128;
    float su = 0.f, qu = 0.f;
#pragma unroll
    for (int s = 0; s < NSLOT; ++s) {
        su += sb[s * 128 + c];
        qu += sb[s * 128 + 64 + c];
    }
    const float inv = 1.0f / (float)(NB * NN);
    float mu = su * inv;
    float var = qu * inv - mu * mu;
    float g = layer ? g1[c] : g0[c];
    float be = layer ? be1[c] : be0[c];
    float sc = g / sqrtf(var + 1e-5f);
    st[layer * 128 + c] = sc;
    st[layer * 128 + 64 + c] = fmaf(-mu, sc, be);
}

// ---------------- global_sort_pool: register top-30 on compact score array ----
__global__ __launch_bounds__(1024) void k_toppool(const float* __restrict__ sc, int* order) {
    __shared__ unsigned long long wbest[16];
    __shared__ unsigned long long winner;
    int b = blockIdx.x, tid = threadIdx.x;
    int g = b >> 2, bi = b & 3;
    int lane = tid & 63, wid = tid >> 6;
    unsigned long long key[5];
#pragma unroll
    for (int j = 0; j < 5; ++j) {
        int n = tid + j * 1024;
        unsigned long long k = 0;
        if (n < NN) {
            float v = sc[((size_t)g * NN + n) * GB + bi];   // already relu'd
            k = ((unsigned long long)__float_as_uint(v) << 32) | (unsigned int)(NN - n);
        }
        key[j] = k;
    }
    for (int k = 0; k < KPOOL; ++k) {
        unsigned long long best = key[0];
#pragma unroll
        for (int j = 1; j < 5; ++j) best = (key[j] > best) ? key[j] : best;
#pragma unroll
        for (int off = 1; off < 64; off <<= 1) {
            unsigned long long o = __shfl_xor(best, off);
            best = (o > best) ? o : best;
        }
        if (lane == 0) wbest[wid] = best;
        __syncthreads();
        if (tid == 0) {
            unsigned long long w = wbest[0];
#pragma unroll
            for (int i = 1; i < 16; ++i) w = (wbest[i] > w) ? wbest[i] : w;
            winner = w;
            order[b * KPOOL + k] = NN - (int)(w & 0xFFFFFFFFu);
        }
        __syncthreads();
        int n = NN - (int)(winner & 0xFFFFFFFFu);
        if ((n & 1023) == tid) key[n >> 10] = 0;   // remove winner (owner thread)
    }
}

// ---------------- gather selected nodes into flat (B, 6241) ----------------
// h3 branch does the DEFERRED layer-2 GEMM (64 wide) from agg — only 960
// (b,node) pairs ever need it.
__global__ void k_gather(const float* __restrict__ xt, const float* __restrict__ h1,
                         const float* __restrict__ h2, const float* __restrict__ agg,
                         const float* __restrict__ W2, const float* __restrict__ b2,
                         const float* __restrict__ st, const float* __restrict__ age,
                         const int* __restrict__ order, float* __restrict__ flat) {
    int bk = blockIdx.x;
    int b = bk / KPOOL, k = bk % KPOOL;
    int n = order[bk];
    int g = b >> 2, bi = b & 3;
    size_t node = (size_t)g * NN + n;
    int f = threadIdx.x;
    float val = 0.f;
    if (f < DIN) {
        val = xt[(node * GB + bi) * DIN + f];
    } else if (f < DIN + CH) {
        int c = f - DIN;
        val = fmaxf(fmaf(h1[(node * GB + bi) * CH + c], st[c], st[64 + c]), 0.f);
    } else if (f < DIN + 2 * CH) {
        int c = f - DIN - CH;
        val = fmaxf(fmaf(h2[(node * GB + bi) * CH + c], st[128 + c], st[192 + c]), 0.f);
    } else if (f < FTOT) {
        int c = f - DIN - 2 * CH;
        const float* __restrict__ Ar = agg + (node * GB + bi) * CH;
        float s = b2[c];
#pragma unroll 8
        for (int kk = 0; kk < 64; ++kk)
            s = fmaf(Ar[kk], W2[kk * 64 + c], s);   // Ar broadcast, W2 coalesced
        val = fmaxf(s, 0.f);
    }
    if (f < FTOT) flat[(size_t)b * FLATW + k * FTOT + f] = val;
    if (bk == 0 && f >= FTOT && f < FTOT + NB)
        flat[(size_t)(f - FTOT) * FLATW + (FLATW - 1)] = age[f - FTOT];
}

// ---------------- MLP head layer 1: hm += flat @ mW0 (k-split, atomics) ----------------
__global__ void k_head1(const float* __restrict__ flat, const float* __restrict__ mW0,
                        float* hm) {
    int tid = threadIdx.x;
    int j4 = (tid & 31) * 4;       // 32 groups * 4 = 128 cols
    int b0 = (tid >> 5) * 4;       // 8 groups * 4 = 32 rows
    int kbase = blockIdx.x * 64;
    float acc[4][4];
#pragma unroll
    for (int i = 0; i < 4; i++)
#pragma unroll
        for (int jj = 0; jj < 4; jj++) acc[i][jj] = 0.f;
    int kend = FLATW - kbase; if (kend > 64) kend = 64;
    for (int kk = 0; kk < kend; ++kk) {
        int k = kbase + kk;
        float4 w = *(const float4*)(mW0 + (size_t)k * NH + j4);
#pragma unroll
        for (int i = 0; i < 4; i++) {
            float fv = flat[(size_t)(b0 + i) * FLATW + k];
            acc[i][0] = fmaf(fv, w.x, acc[i][0]);
            acc[i][1] = fmaf(fv, w.y, acc[i][1]);
            acc[i][2] = fmaf(fv, w.z, acc[i][2]);
            acc[i][3] = fmaf(fv, w.w, acc[i][3]);
        }
    }
#pragma unroll
    for (int i = 0; i < 4; i++)
#pragma unroll
        for (int jj = 0; jj < 4; jj++)
            atomicAdd(&hm[(size_t)(b0 + i) * NH + j4 + jj], acc[i][jj]);
}

// ---------------- head layer 2 + log_softmax ----------------
__global__ void k_head2(const float* __restrict__ hm, const float* __restrict__ mb0,
                        const float* __restrict__ mW1, const float* __restrict__ mb1,
                        float* __restrict__ out) {
    __shared__ float vals[64];
    int tid = threadIdx.x;  // 64 = 32 b * 2 o
    int b = tid >> 1, o = tid & 1;
    float acc = mb1[o];
    for (int j = 0; j < NH; ++j) {
        float hv = fmaxf(hm[b * NH + j] + mb0[j], 0.f);
        acc = fmaf(hv, mW1[j * 2 + o], acc);
    }
    vals[tid] = acc;
    __syncthreads();
    float v0 = vals[b * 2], v1 = vals[b * 2 + 1];
    float m = fmaxf(v0, v1);
    float lse = m + logf(expf(v0 - m) + expf(v1 - m));
    out[tid] = acc - lse;
}

extern "C" void kernel_launch(void* const* d_in, const int* in_sizes, int n_in,
                              void* d_out, int out_size, void* d_ws, size_t ws_size,
                              hipStream_t stream) {
    const float* x    = (const float*)d_in[0];
    const float* age  = (const float*)d_in[1];
    const float* attr = (const float*)d_in[2];
    const float* W0   = (const float*)d_in[3];
    const float* b0   = (const float*)d_in[4];
    const float* W1   = (const float*)d_in[5];
    const float* b1   = (const float*)d_in[6];
    const float* W2   = (const float*)d_in[7];
    const float* b2   = (const float*)d_in[8];
    const float* g0   = (const float*)d_in[9];
    const float* be0  = (const float*)d_in[10];
    const float* g1   = (const float*)d_in[11];
    const float* be1  = (const float*)d_in[12];
    const float* mW0  = (const float*)d_in[13];
    const float* mb0  = (const float*)d_in[14];
    const float* mW1  = (const float*)d_in[15];
    const float* mb1  = (const float*)d_in[16];
    const int* erow   = (const int*)d_in[17];
    const int* ecol   = (const int*)d_in[18];
    float* out = (float*)d_out;

    // workspace layout (floats); all float4-aligned
    float* ws     = (float*)d_ws;
    float* deg    = ws;                                  // 5008
    float* dinv   = deg + 5008;                          // 5008
    int*   counts = (int*)(dinv + 5008);                 // 5008
    int*   rowptr = counts + 5008;                       // 5008
    int*   cursor = rowptr + 5008;                       // 5008
    int*   perm   = cursor + 5008;                       // 5008
    int*   csr_col= perm + 5008;                         // NEPAD
    float* csr_nv = (float*)(csr_col + NEPAD);           // NEPAD
    float* stats  = csr_nv + NEPAD;                      // 2*32*128 = 8192
    float* st     = stats + 2 * NSLOT * 128;             // 256 (s0,t0,s1,t1)
    float* sc     = st + 256;                            // NB*NN = 160000 (scores)
    int*   order  = (int*)(sc + NB * NN);                // 960
    float* flat   = (float*)(order + 960);               // 32*6241
    float* hm     = flat + (size_t)NB * FLATW;           // 4096
    float* xt     = hm + 4096;                           // (G8,N,4,16)
    float* h1     = xt + (size_t)NB * NN * DIN;          // (G8,N,4,64) each
    float* h2     = h1 + (size_t)NB * NN * CH;
    float* agg    = h2 + (size_t)NB * NN * CH;           // layer-2 aggregate (pre-GEMM)

    // graph build
    k_init<<<32, 256, 0, stream>>>(deg, counts, stats, hm, perm);
    k_edgetr<<<NEB + (NB * NN + 255) / 256, 256, 0, stream>>>(attr, erow, deg, counts, x, xt);
    k_scan<<<1, 1024, 0, stream>>>(counts, deg, rowptr, cursor, dinv, perm);
    k_build<<<(NE + NN + 255) / 256, 256, 0, stream>>>(erow, ecol, attr, dinv, counts, rowptr, cursor, csr_col, csr_nv);

    const int NBLK = ((NN + NPB - 1) / NPB) * NG;   // 313 * 8
    // fused layers (gather + per-wave GEMM + slot-spread BN stats + inline BN-in)
    k_layer<16, 0, 1, 0><<<NBLK, 256, 0, stream>>>(xt, nullptr, nullptr, nullptr, W0, b0, rowptr, csr_col, csr_nv, dinv, perm, h1, stats, nullptr);
    k_layer<64, 1, 1, 0><<<NBLK, 256, 0, stream>>>(h1, stats, g0, be0, W1, b1, rowptr, csr_col, csr_nv, dinv, perm, h2, stats + NSLOT * 128, nullptr);
    k_layer<64, 1, 0, 1><<<NBLK, 256, 0, stream>>>(h2, stats + NSLOT * 128, g1, be1, W2, b2, rowptr, csr_col, csr_nv, dinv, perm, agg, nullptr, sc);

    // bn scale/shift for gather + sort-pool + gather (deferred GEMM) + head
    k_bnfin<<<1, 128, 0, stream>>>(stats, g0, be0, g1, be1, st);
    k_toppool<<<NB, 1024, 0, stream>>>(sc, order);
    k_gather<<<NB * KPOOL, 256, 0, stream>>>(xt, h1, h2, agg, W2, b2, st, age, order, flat);
    k_head1<<<(FLATW + 63) / 64, 256, 0, stream>>>(flat, mW0, hm);
    k_head2<<<1, 64, 0, stream>>>(hm, mb0, mW1, mb1, out);
}